// Round 1
// baseline (720.768 us; speedup 1.0000x reference)
//
#include <hip/hip_runtime.h>
#include <math.h>

#define NN 50000
#define EE 1600000
#define IN_DIM 256
#define H_DIM 64
#define C_DIM 16
#define NT 5000

// ---------------- CSR build ----------------

__global__ __launch_bounds__(256) void zero_kernel(int* __restrict__ cnt, float* __restrict__ loss_ws) {
    int i = blockIdx.x * 256 + threadIdx.x;
    if (i < NN) cnt[i] = 0;
    if (i == 0) *(int*)loss_ws = 0;
}

__global__ __launch_bounds__(256) void hist_kernel(const int* __restrict__ dst, int* __restrict__ cnt) {
    int e = blockIdx.x * 256 + threadIdx.x;
    if (e < EE) atomicAdd(&cnt[dst[e]], 1);
}

// Single-block exclusive scan of cnt -> row_ptr (+ cursor copy, + dinv = rsqrt(deg))
__global__ __launch_bounds__(1024) void scan_kernel(const int* __restrict__ cnt, int* __restrict__ row_ptr,
                                                    int* __restrict__ cursor, float* __restrict__ dinv) {
    const int T = 1024;
    const int SEG = (NN + T - 1) / T;  // 49
    int t = threadIdx.x;
    int begin = t * SEG;
    int endi = begin + SEG; if (endi > NN) endi = NN;
    int s = 0;
    for (int i = begin; i < endi; ++i) s += cnt[i];
    __shared__ int ps[1024];
    ps[t] = s;
    __syncthreads();
    for (int off = 1; off < T; off <<= 1) {
        int v = (t >= off) ? ps[t - off] : 0;
        __syncthreads();
        ps[t] += v;
        __syncthreads();
    }
    int run = (t == 0) ? 0 : ps[t - 1];
    for (int i = begin; i < endi; ++i) {
        row_ptr[i] = run; cursor[i] = run;
        int c = cnt[i];
        run += c;
        dinv[i] = rsqrtf((float)(c + 1));  // +1 self-loop
    }
    if (t == T - 1) row_ptr[NN] = run;
}

__global__ __launch_bounds__(256) void fill_kernel(const int* __restrict__ src, const int* __restrict__ dst,
                                                   int* __restrict__ cursor, int* __restrict__ col) {
    int e = blockIdx.x * 256 + threadIdx.x;
    if (e < EE) {
        int p = atomicAdd(&cursor[dst[e]], 1);
        col[p] = src[e];
    }
}

// ---------------- GEMM: y[r][h] = (sum_k x[r][k] * W[k][h]) * dinv[r] ----------------
// block = 256 threads, 16 rows per block, each thread computes 4 (row,h) outputs.
template <int K, int KC>
__global__ __launch_bounds__(256) void gemm_scale(const float* __restrict__ x, const float* __restrict__ Wg,
                                                  const float* __restrict__ dinv, float* __restrict__ y) {
    __shared__ float Wl[KC * 64];
    __shared__ float Xl[16 * K];
    const int tid = threadIdx.x;
    const int row0 = blockIdx.x * 16;

    // stage 16 rows of x: 16*K floats = 4*K float4
    for (int i = tid; i < 4 * K; i += 256)
        ((float4*)Xl)[i] = ((const float4*)(x + (size_t)row0 * K))[i];

    const int h = tid & 63, rg = tid >> 6;
    float acc[4] = {0.f, 0.f, 0.f, 0.f};

    for (int kc = 0; kc < K; kc += KC) {
        __syncthreads();  // protect Wl (prev chunk readers) + ensure Xl staged on first iter
        for (int i = tid; i < KC * 16; i += 256)
            ((float4*)Wl)[i] = ((const float4*)(Wg + kc * 64))[i];
        __syncthreads();
        for (int k = 0; k < KC; k += 4) {
            float w0 = Wl[(k + 0) * 64 + h];
            float w1 = Wl[(k + 1) * 64 + h];
            float w2 = Wl[(k + 2) * 64 + h];
            float w3 = Wl[(k + 3) * 64 + h];
#pragma unroll
            for (int j = 0; j < 4; ++j) {
                const float4 f = *(const float4*)&Xl[(rg + 4 * j) * K + (kc + k)];
                acc[j] += f.x * w0 + f.y * w1 + f.z * w2 + f.w * w3;
            }
        }
    }
#pragma unroll
    for (int j = 0; j < 4; ++j) {
        int r = row0 + rg + 4 * j;
        y[(size_t)r * 64 + h] = acc[j] * dinv[r];
    }
}

// ---------------- Aggregate: out[d][h] = act(dinv[d]*(y[d][h] + sum_in y[src][h]) + b[h]) ----------------
__global__ __launch_bounds__(256) void aggregate_kernel(const float* __restrict__ y, const int* __restrict__ row_ptr,
                                                        const int* __restrict__ col, const float* __restrict__ dinv,
                                                        const float* __restrict__ b, float* __restrict__ out, int relu) {
    int wv = threadIdx.x >> 6, h = threadIdx.x & 63;
    int d = blockIdx.x * 4 + wv;
    int s0 = row_ptr[d], s1 = row_ptr[d + 1];
    float acc = y[(size_t)d * 64 + h];  // self-loop
    int e = s0;
    for (; e + 4 <= s1; e += 4) {
        int a0 = col[e], a1 = col[e + 1], a2 = col[e + 2], a3 = col[e + 3];
        float v0 = y[(size_t)a0 * 64 + h];
        float v1 = y[(size_t)a1 * 64 + h];
        float v2 = y[(size_t)a2 * 64 + h];
        float v3 = y[(size_t)a3 * 64 + h];
        acc += (v0 + v1) + (v2 + v3);
    }
    for (; e < s1; ++e) acc += y[(size_t)col[e] * 64 + h];
    float r = dinv[d] * acc + b[h];
    if (relu) r = fmaxf(r, 0.f);
    out[(size_t)d * 64 + h] = r;
}

// ---------------- Tail: L2-normalize rows, logits, log_softmax, write pred + h ----------------
__global__ __launch_bounds__(256) void final_kernel(const float* __restrict__ h2, const float* __restrict__ W3,
                                                    const float* __restrict__ b3, float* __restrict__ out) {
    int tid = threadIdx.x;
    int wv = tid >> 6, lane = tid & 63;
    int d = blockIdx.x * 4 + wv;
    float v = h2[(size_t)d * 64 + lane];
    float sq = v * v;
#pragma unroll
    for (int off = 32; off > 0; off >>= 1) sq += __shfl_xor(sq, off);
    float inv = 1.0f / fmaxf(sqrtf(sq), 1e-12f);
    float hn = v * inv;
    out[1 + (size_t)NN * C_DIM + (size_t)d * 64 + lane] = hn;

    __shared__ float hl[4][64];
    hl[wv][lane] = hn;
    __syncthreads();

    // lane = chunk*16 + c : partial dot over 16 h-values, then reduce across the 4 chunks
    int c = lane & 15, chunk = lane >> 4;
    float part = 0.f;
#pragma unroll
    for (int q = 0; q < 16; ++q) {
        int hh = chunk * 16 + q;
        part += hl[wv][hh] * W3[hh * 16 + c];
    }
    part += __shfl_xor(part, 16);
    part += __shfl_xor(part, 32);
    float logit = part + b3[c];

    // log_softmax across the 16 classes (classes live in the low 4 lane bits)
    float m = logit;
#pragma unroll
    for (int off = 8; off > 0; off >>= 1) m = fmaxf(m, __shfl_xor(m, off));
    float ex = __expf(logit - m);
    float se = ex;
#pragma unroll
    for (int off = 8; off > 0; off >>= 1) se += __shfl_xor(se, off);
    float pred = logit - m - __logf(se);
    if (lane < 16) out[1 + (size_t)d * 16 + lane] = pred;
}

__global__ __launch_bounds__(256) void loss_kernel(const float* __restrict__ out, const int* __restrict__ labels,
                                                   const int* __restrict__ train_idx, float* __restrict__ loss_ws) {
    int i = blockIdx.x * 256 + threadIdx.x;
    float v = 0.f;
    if (i < NT) {
        int idx = train_idx[i];
        int lab = labels[idx];
        v = -out[1 + (size_t)idx * 16 + lab];
    }
#pragma unroll
    for (int off = 32; off > 0; off >>= 1) v += __shfl_xor(v, off);
    __shared__ float ws4[4];
    int wv = threadIdx.x >> 6, lane = threadIdx.x & 63;
    if (lane == 0) ws4[wv] = v;
    __syncthreads();
    if (threadIdx.x == 0) atomicAdd(loss_ws, ws4[0] + ws4[1] + ws4[2] + ws4[3]);
}

__global__ void finalize_kernel(const float* __restrict__ loss_ws, float* __restrict__ out) {
    if (threadIdx.x == 0) out[0] = loss_ws[0] * (1.0f / NT);
}

// ---------------- launch ----------------

extern "C" void kernel_launch(void* const* d_in, const int* in_sizes, int n_in,
                              void* d_out, int out_size, void* d_ws, size_t ws_size,
                              hipStream_t stream) {
    const float* feats = (const float*)d_in[0];
    const float* W1 = (const float*)d_in[1];
    const float* b1 = (const float*)d_in[2];
    const float* W2 = (const float*)d_in[3];
    const float* b2 = (const float*)d_in[4];
    const float* W3 = (const float*)d_in[5];
    const float* b3 = (const float*)d_in[6];
    const int* edge_list = (const int*)d_in[7];
    const int* labels = (const int*)d_in[8];
    const int* train_idx = (const int*)d_in[9];
    float* out = (float*)d_out;

    char* w = (char*)d_ws;
    auto alloc = [&](size_t bytes) {
        char* p = w;
        w += (bytes + 255) & ~(size_t)255;
        return p;
    };
    int* cnt = (int*)alloc((size_t)NN * 4);
    int* cursor = (int*)alloc((size_t)NN * 4);
    int* row_ptr = (int*)alloc((size_t)(NN + 1) * 4);
    int* col = (int*)alloc((size_t)EE * 4);
    float* dinv = (float*)alloc((size_t)NN * 4);
    float* bufA = (float*)alloc((size_t)NN * H_DIM * 4);
    float* bufB = (float*)alloc((size_t)NN * H_DIM * 4);
    float* loss_ws = (float*)alloc(4);

    const int* srcp = edge_list;
    const int* dstp = edge_list + EE;

    zero_kernel<<<(NN + 255) / 256, 256, 0, stream>>>(cnt, loss_ws);
    hist_kernel<<<(EE + 255) / 256, 256, 0, stream>>>(dstp, cnt);
    scan_kernel<<<1, 1024, 0, stream>>>(cnt, row_ptr, cursor, dinv);
    fill_kernel<<<(EE + 255) / 256, 256, 0, stream>>>(srcp, dstp, cursor, col);

    // layer 0: feats @ W1, no relu
    gemm_scale<256, 128><<<NN / 16, 256, 0, stream>>>(feats, W1, dinv, bufA);
    aggregate_kernel<<<NN / 4, 256, 0, stream>>>(bufA, row_ptr, col, dinv, b1, bufB, 0);
    // layer 1: relu
    gemm_scale<64, 64><<<NN / 16, 256, 0, stream>>>(bufB, W2, dinv, bufA);
    aggregate_kernel<<<NN / 4, 256, 0, stream>>>(bufA, row_ptr, col, dinv, b2, bufB, 1);
    // layer 2: relu
    gemm_scale<64, 64><<<NN / 16, 256, 0, stream>>>(bufB, W2 + H_DIM * H_DIM, dinv, bufA);
    aggregate_kernel<<<NN / 4, 256, 0, stream>>>(bufA, row_ptr, col, dinv, b2 + H_DIM, bufB, 1);

    final_kernel<<<NN / 4, 256, 0, stream>>>(bufB, W3, b3, out);
    loss_kernel<<<(NT + 255) / 256, 256, 0, stream>>>(out, labels, train_idx, loss_ws);
    finalize_kernel<<<1, 64, 0, stream>>>(loss_ws, out);
}

// Round 2
// 590.046 us; speedup vs baseline: 1.2215x; 1.2215x over previous
//
#include <hip/hip_runtime.h>
#include <math.h>

#define NN 50000
#define EE 1600000
#define IN_DIM 256
#define H_DIM 64
#define C_DIM 16
#define NT 5000
#define NB 196  // ceil(NN/256)

// ---------------- CSR build ----------------

__global__ __launch_bounds__(256) void zero_kernel(int* __restrict__ cnt, float* __restrict__ loss_ws) {
    int i = blockIdx.x * 256 + threadIdx.x;
    if (i < NN) cnt[i] = 0;
    if (i == 0) *(int*)loss_ws = 0;
}

__global__ __launch_bounds__(256) void hist_kernel(const int* __restrict__ dst, int* __restrict__ cnt) {
    int e = blockIdx.x * 256 + threadIdx.x;
    if (e < EE) atomicAdd(&cnt[dst[e]], 1);
}

// Phase 1: per-block (256-wide) exclusive scan of cnt -> row_ptr (local), block totals -> bsum
__global__ __launch_bounds__(256) void scan_blocks(const int* __restrict__ cnt, int* __restrict__ row_ptr,
                                                   int* __restrict__ bsum) {
    int t = threadIdx.x;
    int i = blockIdx.x * 256 + t;
    int orig = (i < NN) ? cnt[i] : 0;
    int v = orig;
    int lane = t & 63, wv = t >> 6;
#pragma unroll
    for (int off = 1; off < 64; off <<= 1) {
        int u = __shfl_up(v, off);
        if (lane >= off) v += u;
    }
    __shared__ int wsum[4];
    if (lane == 63) wsum[wv] = v;
    __syncthreads();
    if (t == 0) {
        int r = 0;
#pragma unroll
        for (int k = 0; k < 4; ++k) { int c = wsum[k]; wsum[k] = r; r += c; }
    }
    __syncthreads();
    int incl = v + wsum[wv];
    if (i < NN) row_ptr[i] = incl - orig;  // local exclusive
    if (t == 255) bsum[blockIdx.x] = incl;
}

// Phase 2: single tiny block scans the 196 block sums (exclusive), total -> bsum_scan[NB]
__global__ __launch_bounds__(256) void scan_bsums(const int* __restrict__ bsum, int* __restrict__ bscan) {
    int t = threadIdx.x;
    int v = (t < NB) ? bsum[t] : 0;
    int orig = v;
    int lane = t & 63, wv = t >> 6;
#pragma unroll
    for (int off = 1; off < 64; off <<= 1) {
        int u = __shfl_up(v, off);
        if (lane >= off) v += u;
    }
    __shared__ int wsum[4];
    if (lane == 63) wsum[wv] = v;
    __syncthreads();
    if (t == 0) {
        int r = 0;
#pragma unroll
        for (int k = 0; k < 4; ++k) { int c = wsum[k]; wsum[k] = r; r += c; }
    }
    __syncthreads();
    int incl = v + wsum[wv];
    if (t < NB) bscan[t] = incl - orig;
    if (t == NB - 1) bscan[NB] = incl;  // grand total == EE
}

// Phase 3: add block offsets; emit row_ptr, cursor, dinv, row_ptr[NN]
__global__ __launch_bounds__(256) void scan_finish(const int* __restrict__ cnt, const int* __restrict__ bscan,
                                                   int* __restrict__ row_ptr, int* __restrict__ cursor,
                                                   float* __restrict__ dinv) {
    int i = blockIdx.x * 256 + threadIdx.x;
    if (i < NN) {
        int r = row_ptr[i] + bscan[blockIdx.x];
        row_ptr[i] = r;
        cursor[i] = r;
        dinv[i] = rsqrtf((float)(cnt[i] + 1));  // +1 self-loop
    }
    if (i == 0) row_ptr[NN] = bscan[NB];
}

__global__ __launch_bounds__(256) void fill_kernel(const int* __restrict__ src, const int* __restrict__ dst,
                                                   int* __restrict__ cursor, int* __restrict__ col) {
    int e = blockIdx.x * 256 + threadIdx.x;
    if (e < EE) {
        int p = atomicAdd(&cursor[dst[e]], 1);
        col[p] = src[e];
    }
}

// ---------------- GEMM: y[r][h] = (sum_k x[r][k] * W[k][h]) * dinv[r] ----------------
template <int K, int KC>
__global__ __launch_bounds__(256) void gemm_scale(const float* __restrict__ x, const float* __restrict__ Wg,
                                                  const float* __restrict__ dinv, float* __restrict__ y) {
    __shared__ float Wl[KC * 64];
    __shared__ float Xl[16 * K];
    const int tid = threadIdx.x;
    const int row0 = blockIdx.x * 16;

    for (int i = tid; i < 4 * K; i += 256)
        ((float4*)Xl)[i] = ((const float4*)(x + (size_t)row0 * K))[i];

    const int h = tid & 63, rg = tid >> 6;
    float acc[4] = {0.f, 0.f, 0.f, 0.f};

    for (int kc = 0; kc < K; kc += KC) {
        __syncthreads();
        for (int i = tid; i < KC * 16; i += 256)
            ((float4*)Wl)[i] = ((const float4*)(Wg + kc * 64))[i];
        __syncthreads();
        for (int k = 0; k < KC; k += 4) {
            float w0 = Wl[(k + 0) * 64 + h];
            float w1 = Wl[(k + 1) * 64 + h];
            float w2 = Wl[(k + 2) * 64 + h];
            float w3 = Wl[(k + 3) * 64 + h];
#pragma unroll
            for (int j = 0; j < 4; ++j) {
                const float4 f = *(const float4*)&Xl[(rg + 4 * j) * K + (kc + k)];
                acc[j] += f.x * w0 + f.y * w1 + f.z * w2 + f.w * w3;
            }
        }
    }
#pragma unroll
    for (int j = 0; j < 4; ++j) {
        int r = row0 + rg + 4 * j;
        y[(size_t)r * 64 + h] = acc[j] * dinv[r];
    }
}

// ---------------- Aggregate: out[d][h] = act(dinv[d]*(y[d][h] + sum_in y[src][h]) + b[h]) ----------------
__global__ __launch_bounds__(256) void aggregate_kernel(const float* __restrict__ y, const int* __restrict__ row_ptr,
                                                        const int* __restrict__ col, const float* __restrict__ dinv,
                                                        const float* __restrict__ b, float* __restrict__ out, int relu) {
    int wv = threadIdx.x >> 6, h = threadIdx.x & 63;
    int d = blockIdx.x * 4 + wv;
    int s0 = row_ptr[d], s1 = row_ptr[d + 1];
    float acc = y[(size_t)d * 64 + h];  // self-loop
    int e = s0;
    for (; e + 4 <= s1; e += 4) {
        int a0 = col[e], a1 = col[e + 1], a2 = col[e + 2], a3 = col[e + 3];
        float v0 = y[(size_t)a0 * 64 + h];
        float v1 = y[(size_t)a1 * 64 + h];
        float v2 = y[(size_t)a2 * 64 + h];
        float v3 = y[(size_t)a3 * 64 + h];
        acc += (v0 + v1) + (v2 + v3);
    }
    for (; e < s1; ++e) acc += y[(size_t)col[e] * 64 + h];
    float r = dinv[d] * acc + b[h];
    if (relu) r = fmaxf(r, 0.f);
    out[(size_t)d * 64 + h] = r;
}

// ---------------- Tail ----------------
__global__ __launch_bounds__(256) void final_kernel(const float* __restrict__ h2, const float* __restrict__ W3,
                                                    const float* __restrict__ b3, float* __restrict__ out) {
    int tid = threadIdx.x;
    int wv = tid >> 6, lane = tid & 63;
    int d = blockIdx.x * 4 + wv;
    float v = h2[(size_t)d * 64 + lane];
    float sq = v * v;
#pragma unroll
    for (int off = 32; off > 0; off >>= 1) sq += __shfl_xor(sq, off);
    float inv = 1.0f / fmaxf(sqrtf(sq), 1e-12f);
    float hn = v * inv;
    out[1 + (size_t)NN * C_DIM + (size_t)d * 64 + lane] = hn;

    __shared__ float hl[4][64];
    hl[wv][lane] = hn;
    __syncthreads();

    int c = lane & 15, chunk = lane >> 4;
    float part = 0.f;
#pragma unroll
    for (int q = 0; q < 16; ++q) {
        int hh = chunk * 16 + q;
        part += hl[wv][hh] * W3[hh * 16 + c];
    }
    part += __shfl_xor(part, 16);
    part += __shfl_xor(part, 32);
    float logit = part + b3[c];

    float m = logit;
#pragma unroll
    for (int off = 8; off > 0; off >>= 1) m = fmaxf(m, __shfl_xor(m, off));
    float ex = __expf(logit - m);
    float se = ex;
#pragma unroll
    for (int off = 8; off > 0; off >>= 1) se += __shfl_xor(se, off);
    float pred = logit - m - __logf(se);
    if (lane < 16) out[1 + (size_t)d * 16 + lane] = pred;
}

__global__ __launch_bounds__(256) void loss_kernel(const float* __restrict__ out, const int* __restrict__ labels,
                                                   const int* __restrict__ train_idx, float* __restrict__ loss_ws) {
    int i = blockIdx.x * 256 + threadIdx.x;
    float v = 0.f;
    if (i < NT) {
        int idx = train_idx[i];
        int lab = labels[idx];
        v = -out[1 + (size_t)idx * 16 + lab];
    }
#pragma unroll
    for (int off = 32; off > 0; off >>= 1) v += __shfl_xor(v, off);
    __shared__ float ws4[4];
    int wv = threadIdx.x >> 6, lane = threadIdx.x & 63;
    if (lane == 0) ws4[wv] = v;
    __syncthreads();
    if (threadIdx.x == 0) atomicAdd(loss_ws, ws4[0] + ws4[1] + ws4[2] + ws4[3]);
}

__global__ void finalize_kernel(const float* __restrict__ loss_ws, float* __restrict__ out) {
    if (threadIdx.x == 0) out[0] = loss_ws[0] * (1.0f / NT);
}

// ---------------- launch ----------------

extern "C" void kernel_launch(void* const* d_in, const int* in_sizes, int n_in,
                              void* d_out, int out_size, void* d_ws, size_t ws_size,
                              hipStream_t stream) {
    const float* feats = (const float*)d_in[0];
    const float* W1 = (const float*)d_in[1];
    const float* b1 = (const float*)d_in[2];
    const float* W2 = (const float*)d_in[3];
    const float* b2 = (const float*)d_in[4];
    const float* W3 = (const float*)d_in[5];
    const float* b3 = (const float*)d_in[6];
    const int* edge_list = (const int*)d_in[7];
    const int* labels = (const int*)d_in[8];
    const int* train_idx = (const int*)d_in[9];
    float* out = (float*)d_out;

    char* w = (char*)d_ws;
    auto alloc = [&](size_t bytes) {
        char* p = w;
        w += (bytes + 255) & ~(size_t)255;
        return p;
    };
    int* cnt = (int*)alloc((size_t)NN * 4);
    int* cursor = (int*)alloc((size_t)NN * 4);
    int* row_ptr = (int*)alloc((size_t)(NN + 1) * 4);
    int* col = (int*)alloc((size_t)EE * 4);
    float* dinv = (float*)alloc((size_t)NN * 4);
    float* bufA = (float*)alloc((size_t)NN * H_DIM * 4);
    float* bufB = (float*)alloc((size_t)NN * H_DIM * 4);
    float* loss_ws = (float*)alloc(4);
    int* bsum = (int*)alloc((size_t)NB * 4);
    int* bscan = (int*)alloc((size_t)(NB + 1) * 4);

    const int* srcp = edge_list;
    const int* dstp = edge_list + EE;

    zero_kernel<<<NB, 256, 0, stream>>>(cnt, loss_ws);
    hist_kernel<<<(EE + 255) / 256, 256, 0, stream>>>(dstp, cnt);
    scan_blocks<<<NB, 256, 0, stream>>>(cnt, row_ptr, bsum);
    scan_bsums<<<1, 256, 0, stream>>>(bsum, bscan);
    scan_finish<<<NB, 256, 0, stream>>>(cnt, bscan, row_ptr, cursor, dinv);
    fill_kernel<<<(EE + 255) / 256, 256, 0, stream>>>(srcp, dstp, cursor, col);

    // layer 0: feats @ W1, no relu
    gemm_scale<256, 128><<<NN / 16, 256, 0, stream>>>(feats, W1, dinv, bufA);
    aggregate_kernel<<<NN / 4, 256, 0, stream>>>(bufA, row_ptr, col, dinv, b1, bufB, 0);
    // layer 1: relu
    gemm_scale<64, 64><<<NN / 16, 256, 0, stream>>>(bufB, W2, dinv, bufA);
    aggregate_kernel<<<NN / 4, 256, 0, stream>>>(bufA, row_ptr, col, dinv, b2, bufB, 1);
    // layer 2: relu
    gemm_scale<64, 64><<<NN / 16, 256, 0, stream>>>(bufB, W2 + H_DIM * H_DIM, dinv, bufA);
    aggregate_kernel<<<NN / 4, 256, 0, stream>>>(bufA, row_ptr, col, dinv, b2 + H_DIM, bufB, 1);

    final_kernel<<<NN / 4, 256, 0, stream>>>(bufB, W3, b3, out);
    loss_kernel<<<(NT + 255) / 256, 256, 0, stream>>>(out, labels, train_idx, loss_ws);
    finalize_kernel<<<1, 64, 0, stream>>>(loss_ws, out);
}

// Round 3
// 502.617 us; speedup vs baseline: 1.4340x; 1.1739x over previous
//
#include <hip/hip_runtime.h>
#include <math.h>

#define NN 50000
#define EE 1600000
#define IN_DIM 256
#define H_DIM 64
#define C_DIM 16
#define NT 5000
#define NB 196    // ceil(NN/256)
#define NBUK 391  // ceil(NN/128)
#define CHUNK 8192
#define NCHUNK 196  // ceil(EE/CHUNK) = 196 (195*8192=1597440, last chunk 2560)
#define CAP 6144

// ---------------- CSR build ----------------

__global__ __launch_bounds__(256) void zero_kernel(int* __restrict__ cnt, float* __restrict__ loss_ws) {
    int i = blockIdx.x * 256 + threadIdx.x;
    if (i < NN) cnt[i] = 0;
    if (i == 0) *(int*)loss_ws = 0;
}

__global__ __launch_bounds__(256) void hist_kernel(const int* __restrict__ dst, int* __restrict__ cnt) {
    int e = blockIdx.x * 256 + threadIdx.x;
    if (e < EE) atomicAdd(&cnt[dst[e]], 1);
}

// Phase 1: per-block (256-wide) exclusive scan of cnt -> row_ptr (local), block totals -> bsum
__global__ __launch_bounds__(256) void scan_blocks(const int* __restrict__ cnt, int* __restrict__ row_ptr,
                                                   int* __restrict__ bsum) {
    int t = threadIdx.x;
    int i = blockIdx.x * 256 + t;
    int orig = (i < NN) ? cnt[i] : 0;
    int v = orig;
    int lane = t & 63, wv = t >> 6;
#pragma unroll
    for (int off = 1; off < 64; off <<= 1) {
        int u = __shfl_up(v, off);
        if (lane >= off) v += u;
    }
    __shared__ int wsum[4];
    if (lane == 63) wsum[wv] = v;
    __syncthreads();
    if (t == 0) {
        int r = 0;
#pragma unroll
        for (int k = 0; k < 4; ++k) { int c = wsum[k]; wsum[k] = r; r += c; }
    }
    __syncthreads();
    int incl = v + wsum[wv];
    if (i < NN) row_ptr[i] = incl - orig;  // local exclusive
    if (t == 255) bsum[blockIdx.x] = incl;
}

// Phase 2: single tiny block scans the 196 block sums (exclusive), total -> bscan[NB]
__global__ __launch_bounds__(256) void scan_bsums(const int* __restrict__ bsum, int* __restrict__ bscan) {
    int t = threadIdx.x;
    int v = (t < NB) ? bsum[t] : 0;
    int orig = v;
    int lane = t & 63, wv = t >> 6;
#pragma unroll
    for (int off = 1; off < 64; off <<= 1) {
        int u = __shfl_up(v, off);
        if (lane >= off) v += u;
    }
    __shared__ int wsum[4];
    if (lane == 63) wsum[wv] = v;
    __syncthreads();
    if (t == 0) {
        int r = 0;
#pragma unroll
        for (int k = 0; k < 4; ++k) { int c = wsum[k]; wsum[k] = r; r += c; }
    }
    __syncthreads();
    int incl = v + wsum[wv];
    if (t < NB) bscan[t] = incl - orig;
    if (t == NB - 1) bscan[NB] = incl;  // grand total == EE
}

// Phase 3: add block offsets; emit row_ptr, cursor, dinv, bucket_cursor, row_ptr[NN]
__global__ __launch_bounds__(256) void scan_finish(const int* __restrict__ cnt, const int* __restrict__ bscan,
                                                   int* __restrict__ row_ptr, int* __restrict__ cursor,
                                                   float* __restrict__ dinv, int* __restrict__ bucket_cursor) {
    int i = blockIdx.x * 256 + threadIdx.x;
    if (i < NN) {
        int r = row_ptr[i] + bscan[blockIdx.x];
        row_ptr[i] = r;
        cursor[i] = r;
        dinv[i] = rsqrtf((float)(cnt[i] + 1));  // +1 self-loop
        if ((i & 127) == 0) bucket_cursor[i >> 7] = r;
    }
    if (i == 0) row_ptr[NN] = bscan[NB];
}

// Multi-split: bin edges by coarse bucket (dst>>7) with per-block LDS staging, coalesced flush.
// temp layout == col layout at bucket granularity (bucket b region = [row_ptr[128b], row_ptr[128(b+1)])).
__global__ __launch_bounds__(256) void multisplit_kernel(const int* __restrict__ src, const int* __restrict__ dst,
                                                         int* __restrict__ bucket_cursor,
                                                         unsigned int* __restrict__ temp) {
    __shared__ int hist[NBUK];
    __shared__ int excl[NBUK + 1];
    __shared__ int offs[NBUK];
    __shared__ int delta[NBUK];
    __shared__ unsigned short bid[CHUNK];
    __shared__ unsigned int stag[CHUNK];

    const int tid = threadIdx.x;
    const int base_e = blockIdx.x * CHUNK;

    for (int i = tid; i < NBUK; i += 256) hist[i] = 0;
    __syncthreads();

    // Phase A: per-block bucket histogram
    for (int i = tid; i < CHUNK; i += 256) {
        int e = base_e + i;
        if (e < EE) atomicAdd(&hist[dst[e] >> 7], 1);
    }
    __syncthreads();

    // Phase B: exclusive scan of 391 counters by wave 0
    if (tid < 64) {
        int lane = tid;
        int lc[7];
        int s = 0;
#pragma unroll
        for (int k = 0; k < 7; ++k) {
            int idx = lane * 7 + k;
            int c = (idx < NBUK) ? hist[idx] : 0;
            lc[k] = c;
            s += c;
        }
        int v = s;
#pragma unroll
        for (int off = 1; off < 64; off <<= 1) {
            int u = __shfl_up(v, off);
            if (lane >= off) v += u;
        }
        int ex = v - s;
#pragma unroll
        for (int k = 0; k < 7; ++k) {
            int idx = lane * 7 + k;
            if (idx < NBUK) excl[idx] = ex;
            ex += lc[k];
        }
        if (lane == 63) excl[NBUK] = v;
    }
    __syncthreads();

    // Reserve per-bucket global runs
    for (int b = tid; b < NBUK; b += 256) {
        int count = excl[b + 1] - excl[b];
        int gbase = atomicAdd(&bucket_cursor[b], count);
        delta[b] = gbase - excl[b];
        offs[b] = excl[b];
    }
    __syncthreads();

    // Phase C: bin into LDS staging (ordered by bucket)
    for (int i = tid; i < CHUNK; i += 256) {
        int e = base_e + i;
        if (e < EE) {
            int d = dst[e];
            int s = src[e];
            int b = d >> 7;
            int rank = atomicAdd(&offs[b], 1);
            stag[rank] = (unsigned int)(((d & 127) << 16) | s);
            bid[rank] = (unsigned short)b;
        }
    }
    __syncthreads();

    // Phase D: coalesced flush of bucket runs
    int nval = excl[NBUK];
    for (int i = tid; i < nval; i += 256) {
        int b = bid[i];
        temp[delta[b] + i] = stag[i];
    }
}

// Per-bucket sort into exact per-dst CSR order; fully coalesced global I/O.
__global__ __launch_bounds__(256) void bucket_sort_kernel(const unsigned int* __restrict__ temp,
                                                          const int* __restrict__ row_ptr,
                                                          int* __restrict__ cursor, int* __restrict__ col) {
    __shared__ int rp[129];
    __shared__ int cur[128];
    __shared__ int stag[CAP];
    const int b = blockIdx.x;
    const int d0 = b << 7;
    const int d1 = (d0 + 128 < NN) ? d0 + 128 : NN;
    const int nd = d1 - d0;
    const int tid = threadIdx.x;
    for (int j = tid; j <= nd; j += 256) rp[j] = row_ptr[d0 + j];
    __syncthreads();
    const int pos0 = rp[0];
    const int M = rp[nd] - pos0;
    if (tid < nd) cur[tid] = rp[tid] - pos0;
    __syncthreads();
    if (M <= CAP) {
        for (int i = tid; i < M; i += 256) {
            unsigned int v = temp[pos0 + i];
            int dl = (int)(v >> 16);
            int rank = atomicAdd(&cur[dl], 1);
            stag[rank] = (int)(v & 0xFFFFu);
        }
        __syncthreads();
        for (int i = tid; i < M; i += 256) col[pos0 + i] = stag[i];
    } else {
        // statistically unreachable fallback: global per-dst cursors
        for (int i = tid; i < M; i += 256) {
            unsigned int v = temp[pos0 + i];
            int d = d0 + (int)(v >> 16);
            int p = atomicAdd(&cursor[d], 1);
            col[p] = (int)(v & 0xFFFFu);
        }
    }
}

// ---------------- GEMM: y[r][h] = (sum_k x[r][k] * W[k][h]) * dinv[r] ----------------
template <int K, int KC>
__global__ __launch_bounds__(256) void gemm_scale(const float* __restrict__ x, const float* __restrict__ Wg,
                                                  const float* __restrict__ dinv, float* __restrict__ y) {
    __shared__ float Wl[KC * 64];
    __shared__ float Xl[16 * K];
    const int tid = threadIdx.x;
    const int row0 = blockIdx.x * 16;

    for (int i = tid; i < 4 * K; i += 256)
        ((float4*)Xl)[i] = ((const float4*)(x + (size_t)row0 * K))[i];

    const int h = tid & 63, rg = tid >> 6;
    float acc[4] = {0.f, 0.f, 0.f, 0.f};

    for (int kc = 0; kc < K; kc += KC) {
        __syncthreads();
        for (int i = tid; i < KC * 16; i += 256)
            ((float4*)Wl)[i] = ((const float4*)(Wg + kc * 64))[i];
        __syncthreads();
        for (int k = 0; k < KC; k += 4) {
            float w0 = Wl[(k + 0) * 64 + h];
            float w1 = Wl[(k + 1) * 64 + h];
            float w2 = Wl[(k + 2) * 64 + h];
            float w3 = Wl[(k + 3) * 64 + h];
#pragma unroll
            for (int j = 0; j < 4; ++j) {
                const float4 f = *(const float4*)&Xl[(rg + 4 * j) * K + (kc + k)];
                acc[j] += f.x * w0 + f.y * w1 + f.z * w2 + f.w * w3;
            }
        }
    }
#pragma unroll
    for (int j = 0; j < 4; ++j) {
        int r = row0 + rg + 4 * j;
        y[(size_t)r * 64 + h] = acc[j] * dinv[r];
    }
}

// ---------------- Aggregate ----------------
__global__ __launch_bounds__(256) void aggregate_kernel(const float* __restrict__ y, const int* __restrict__ row_ptr,
                                                        const int* __restrict__ col, const float* __restrict__ dinv,
                                                        const float* __restrict__ b, float* __restrict__ out, int relu) {
    int wv = threadIdx.x >> 6, h = threadIdx.x & 63;
    int d = blockIdx.x * 4 + wv;
    int s0 = row_ptr[d], s1 = row_ptr[d + 1];
    float acc = y[(size_t)d * 64 + h];  // self-loop
    int e = s0;
    for (; e + 4 <= s1; e += 4) {
        int a0 = col[e], a1 = col[e + 1], a2 = col[e + 2], a3 = col[e + 3];
        float v0 = y[(size_t)a0 * 64 + h];
        float v1 = y[(size_t)a1 * 64 + h];
        float v2 = y[(size_t)a2 * 64 + h];
        float v3 = y[(size_t)a3 * 64 + h];
        acc += (v0 + v1) + (v2 + v3);
    }
    for (; e < s1; ++e) acc += y[(size_t)col[e] * 64 + h];
    float r = dinv[d] * acc + b[h];
    if (relu) r = fmaxf(r, 0.f);
    out[(size_t)d * 64 + h] = r;
}

// ---------------- Tail ----------------
__global__ __launch_bounds__(256) void final_kernel(const float* __restrict__ h2, const float* __restrict__ W3,
                                                    const float* __restrict__ b3, float* __restrict__ out) {
    int tid = threadIdx.x;
    int wv = tid >> 6, lane = tid & 63;
    int d = blockIdx.x * 4 + wv;
    float v = h2[(size_t)d * 64 + lane];
    float sq = v * v;
#pragma unroll
    for (int off = 32; off > 0; off >>= 1) sq += __shfl_xor(sq, off);
    float inv = 1.0f / fmaxf(sqrtf(sq), 1e-12f);
    float hn = v * inv;
    out[1 + (size_t)NN * C_DIM + (size_t)d * 64 + lane] = hn;

    __shared__ float hl[4][64];
    hl[wv][lane] = hn;
    __syncthreads();

    int c = lane & 15, chunk = lane >> 4;
    float part = 0.f;
#pragma unroll
    for (int q = 0; q < 16; ++q) {
        int hh = chunk * 16 + q;
        part += hl[wv][hh] * W3[hh * 16 + c];
    }
    part += __shfl_xor(part, 16);
    part += __shfl_xor(part, 32);
    float logit = part + b3[c];

    float m = logit;
#pragma unroll
    for (int off = 8; off > 0; off >>= 1) m = fmaxf(m, __shfl_xor(m, off));
    float ex = __expf(logit - m);
    float se = ex;
#pragma unroll
    for (int off = 8; off > 0; off >>= 1) se += __shfl_xor(se, off);
    float pred = logit - m - __logf(se);
    if (lane < 16) out[1 + (size_t)d * 16 + lane] = pred;
}

__global__ __launch_bounds__(256) void loss_kernel(const float* __restrict__ out, const int* __restrict__ labels,
                                                   const int* __restrict__ train_idx, float* __restrict__ loss_ws) {
    int i = blockIdx.x * 256 + threadIdx.x;
    float v = 0.f;
    if (i < NT) {
        int idx = train_idx[i];
        int lab = labels[idx];
        v = -out[1 + (size_t)idx * 16 + lab];
    }
#pragma unroll
    for (int off = 32; off > 0; off >>= 1) v += __shfl_xor(v, off);
    __shared__ float ws4[4];
    int wv = threadIdx.x >> 6, lane = threadIdx.x & 63;
    if (lane == 0) ws4[wv] = v;
    __syncthreads();
    if (threadIdx.x == 0) atomicAdd(loss_ws, ws4[0] + ws4[1] + ws4[2] + ws4[3]);
}

__global__ void finalize_kernel(const float* __restrict__ loss_ws, float* __restrict__ out) {
    if (threadIdx.x == 0) out[0] = loss_ws[0] * (1.0f / NT);
}

// ---------------- launch ----------------

extern "C" void kernel_launch(void* const* d_in, const int* in_sizes, int n_in,
                              void* d_out, int out_size, void* d_ws, size_t ws_size,
                              hipStream_t stream) {
    const float* feats = (const float*)d_in[0];
    const float* W1 = (const float*)d_in[1];
    const float* b1 = (const float*)d_in[2];
    const float* W2 = (const float*)d_in[3];
    const float* b2 = (const float*)d_in[4];
    const float* W3 = (const float*)d_in[5];
    const float* b3 = (const float*)d_in[6];
    const int* edge_list = (const int*)d_in[7];
    const int* labels = (const int*)d_in[8];
    const int* train_idx = (const int*)d_in[9];
    float* out = (float*)d_out;

    char* w = (char*)d_ws;
    auto alloc = [&](size_t bytes) {
        char* p = w;
        w += (bytes + 255) & ~(size_t)255;
        return p;
    };
    int* cnt = (int*)alloc((size_t)NN * 4);
    int* cursor = (int*)alloc((size_t)NN * 4);
    int* row_ptr = (int*)alloc((size_t)(NN + 1) * 4);
    int* col = (int*)alloc((size_t)EE * 4);
    unsigned int* temp = (unsigned int*)alloc((size_t)EE * 4);
    float* dinv = (float*)alloc((size_t)NN * 4);
    float* bufA = (float*)alloc((size_t)NN * H_DIM * 4);
    float* bufB = (float*)alloc((size_t)NN * H_DIM * 4);
    float* loss_ws = (float*)alloc(4);
    int* bsum = (int*)alloc((size_t)NB * 4);
    int* bscan = (int*)alloc((size_t)(NB + 1) * 4);
    int* bucket_cursor = (int*)alloc((size_t)NBUK * 4);

    const int* srcp = edge_list;
    const int* dstp = edge_list + EE;

    zero_kernel<<<NB, 256, 0, stream>>>(cnt, loss_ws);
    hist_kernel<<<(EE + 255) / 256, 256, 0, stream>>>(dstp, cnt);
    scan_blocks<<<NB, 256, 0, stream>>>(cnt, row_ptr, bsum);
    scan_bsums<<<1, 256, 0, stream>>>(bsum, bscan);
    scan_finish<<<NB, 256, 0, stream>>>(cnt, bscan, row_ptr, cursor, dinv, bucket_cursor);
    multisplit_kernel<<<NCHUNK, 256, 0, stream>>>(srcp, dstp, bucket_cursor, temp);
    bucket_sort_kernel<<<NBUK, 256, 0, stream>>>(temp, row_ptr, cursor, col);

    // layer 0: feats @ W1, no relu
    gemm_scale<256, 128><<<NN / 16, 256, 0, stream>>>(feats, W1, dinv, bufA);
    aggregate_kernel<<<NN / 4, 256, 0, stream>>>(bufA, row_ptr, col, dinv, b1, bufB, 0);
    // layer 1: relu
    gemm_scale<64, 64><<<NN / 16, 256, 0, stream>>>(bufB, W2, dinv, bufA);
    aggregate_kernel<<<NN / 4, 256, 0, stream>>>(bufA, row_ptr, col, dinv, b2, bufB, 1);
    // layer 2: relu
    gemm_scale<64, 64><<<NN / 16, 256, 0, stream>>>(bufB, W2 + H_DIM * H_DIM, dinv, bufA);
    aggregate_kernel<<<NN / 4, 256, 0, stream>>>(bufA, row_ptr, col, dinv, b2 + H_DIM, bufB, 1);

    final_kernel<<<NN / 4, 256, 0, stream>>>(bufB, W3, b3, out);
    loss_kernel<<<(NT + 255) / 256, 256, 0, stream>>>(out, labels, train_idx, loss_ws);
    finalize_kernel<<<1, 64, 0, stream>>>(loss_ws, out);
}

// Round 4
// 481.560 us; speedup vs baseline: 1.4967x; 1.0437x over previous
//
#include <hip/hip_runtime.h>
#include <math.h>

#define NN 50000
#define EE 1600000
#define IN_DIM 256
#define H_DIM 64
#define C_DIM 16
#define NT 5000
#define NB 196    // ceil(NN/256)
#define NBUK 391  // ceil(NN/128)
#define CHUNK 8192
#define NCHUNK 196  // ceil(EE/CHUNK)
#define CAP 6144

// ---------------- CSR build ----------------

__global__ __launch_bounds__(256) void zero_kernel(int* __restrict__ cnt, float* __restrict__ loss_ws) {
    int i = blockIdx.x * 256 + threadIdx.x;
    if (i < NN) cnt[i] = 0;
    if (i == 0) *(int*)loss_ws = 0;
}

__global__ __launch_bounds__(256) void hist_kernel(const int* __restrict__ dst, int* __restrict__ cnt) {
    int e = blockIdx.x * 256 + threadIdx.x;
    if (e < EE) atomicAdd(&cnt[dst[e]], 1);
}

__global__ __launch_bounds__(256) void scan_blocks(const int* __restrict__ cnt, int* __restrict__ row_ptr,
                                                   int* __restrict__ bsum) {
    int t = threadIdx.x;
    int i = blockIdx.x * 256 + t;
    int orig = (i < NN) ? cnt[i] : 0;
    int v = orig;
    int lane = t & 63, wv = t >> 6;
#pragma unroll
    for (int off = 1; off < 64; off <<= 1) {
        int u = __shfl_up(v, off);
        if (lane >= off) v += u;
    }
    __shared__ int wsum[4];
    if (lane == 63) wsum[wv] = v;
    __syncthreads();
    if (t == 0) {
        int r = 0;
#pragma unroll
        for (int k = 0; k < 4; ++k) { int c = wsum[k]; wsum[k] = r; r += c; }
    }
    __syncthreads();
    int incl = v + wsum[wv];
    if (i < NN) row_ptr[i] = incl - orig;  // local exclusive
    if (t == 255) bsum[blockIdx.x] = incl;
}

__global__ __launch_bounds__(256) void scan_bsums(const int* __restrict__ bsum, int* __restrict__ bscan) {
    int t = threadIdx.x;
    int v = (t < NB) ? bsum[t] : 0;
    int orig = v;
    int lane = t & 63, wv = t >> 6;
#pragma unroll
    for (int off = 1; off < 64; off <<= 1) {
        int u = __shfl_up(v, off);
        if (lane >= off) v += u;
    }
    __shared__ int wsum[4];
    if (lane == 63) wsum[wv] = v;
    __syncthreads();
    if (t == 0) {
        int r = 0;
#pragma unroll
        for (int k = 0; k < 4; ++k) { int c = wsum[k]; wsum[k] = r; r += c; }
    }
    __syncthreads();
    int incl = v + wsum[wv];
    if (t < NB) bscan[t] = incl - orig;
    if (t == NB - 1) bscan[NB] = incl;  // grand total == EE
}

__global__ __launch_bounds__(256) void scan_finish(const int* __restrict__ cnt, const int* __restrict__ bscan,
                                                   int* __restrict__ row_ptr, int* __restrict__ cursor,
                                                   float* __restrict__ dinv, int* __restrict__ bucket_cursor) {
    int i = blockIdx.x * 256 + threadIdx.x;
    if (i < NN) {
        int r = row_ptr[i] + bscan[blockIdx.x];
        row_ptr[i] = r;
        cursor[i] = r;
        dinv[i] = rsqrtf((float)(cnt[i] + 1));  // +1 self-loop
        if ((i & 127) == 0) bucket_cursor[i >> 7] = r;
    }
    if (i == 0) row_ptr[NN] = bscan[NB];
}

// Multi-split by coarse bucket (dst>>7), LDS staging, coalesced flush.
__global__ __launch_bounds__(256) void multisplit_kernel(const int* __restrict__ src, const int* __restrict__ dst,
                                                         int* __restrict__ bucket_cursor,
                                                         unsigned int* __restrict__ temp) {
    __shared__ int hist[NBUK];
    __shared__ int excl[NBUK + 1];
    __shared__ int offs[NBUK];
    __shared__ int delta[NBUK];
    __shared__ unsigned short bid[CHUNK];
    __shared__ unsigned int stag[CHUNK];

    const int tid = threadIdx.x;
    const int base_e = blockIdx.x * CHUNK;

    for (int i = tid; i < NBUK; i += 256) hist[i] = 0;
    __syncthreads();

    for (int i = tid; i < CHUNK; i += 256) {
        int e = base_e + i;
        if (e < EE) atomicAdd(&hist[dst[e] >> 7], 1);
    }
    __syncthreads();

    if (tid < 64) {
        int lane = tid;
        int lc[7];
        int s = 0;
#pragma unroll
        for (int k = 0; k < 7; ++k) {
            int idx = lane * 7 + k;
            int c = (idx < NBUK) ? hist[idx] : 0;
            lc[k] = c;
            s += c;
        }
        int v = s;
#pragma unroll
        for (int off = 1; off < 64; off <<= 1) {
            int u = __shfl_up(v, off);
            if (lane >= off) v += u;
        }
        int ex = v - s;
#pragma unroll
        for (int k = 0; k < 7; ++k) {
            int idx = lane * 7 + k;
            if (idx < NBUK) excl[idx] = ex;
            ex += lc[k];
        }
        if (lane == 63) excl[NBUK] = v;
    }
    __syncthreads();

    for (int b = tid; b < NBUK; b += 256) {
        int count = excl[b + 1] - excl[b];
        int gbase = atomicAdd(&bucket_cursor[b], count);
        delta[b] = gbase - excl[b];
        offs[b] = excl[b];
    }
    __syncthreads();

    for (int i = tid; i < CHUNK; i += 256) {
        int e = base_e + i;
        if (e < EE) {
            int d = dst[e];
            int s = src[e];
            int b = d >> 7;
            int rank = atomicAdd(&offs[b], 1);
            stag[rank] = (unsigned int)(((d & 127) << 16) | s);
            bid[rank] = (unsigned short)b;
        }
    }
    __syncthreads();

    int nval = excl[NBUK];
    for (int i = tid; i < nval; i += 256) {
        int b = bid[i];
        temp[delta[b] + i] = stag[i];
    }
}

// Per-bucket sort into exact per-dst CSR order; coalesced global I/O.
__global__ __launch_bounds__(256) void bucket_sort_kernel(const unsigned int* __restrict__ temp,
                                                          const int* __restrict__ row_ptr,
                                                          int* __restrict__ cursor, int* __restrict__ col) {
    __shared__ int rp[129];
    __shared__ int cur[128];
    __shared__ int stag[CAP];
    const int b = blockIdx.x;
    const int d0 = b << 7;
    const int d1 = (d0 + 128 < NN) ? d0 + 128 : NN;
    const int nd = d1 - d0;
    const int tid = threadIdx.x;
    for (int j = tid; j <= nd; j += 256) rp[j] = row_ptr[d0 + j];
    __syncthreads();
    const int pos0 = rp[0];
    const int M = rp[nd] - pos0;
    if (tid < nd) cur[tid] = rp[tid] - pos0;
    __syncthreads();
    if (M <= CAP) {
        for (int i = tid; i < M; i += 256) {
            unsigned int v = temp[pos0 + i];
            int dl = (int)(v >> 16);
            int rank = atomicAdd(&cur[dl], 1);
            stag[rank] = (int)(v & 0xFFFFu);
        }
        __syncthreads();
        for (int i = tid; i < M; i += 256) col[pos0 + i] = stag[i];
    } else {
        for (int i = tid; i < M; i += 256) {
            unsigned int v = temp[pos0 + i];
            int d = d0 + (int)(v >> 16);
            int p = atomicAdd(&cursor[d], 1);
            col[p] = (int)(v & 0xFFFFu);
        }
    }
}

// ---------------- GEMM: y[r][h] = (sum_k x[r][k] * W[k][h]) * dinv[r] ----------------
// 64x64 block tile, 256 threads, 4x4 micro-tile per thread, K chunked by 64.
// Xl stride 68 (+row-interleave r=rr*16+tr) keeps inner-loop LDS reads conflict-free.
template <int KTOT>
__global__ __launch_bounds__(256) void gemm_tile(const float* __restrict__ x, const float* __restrict__ Wg,
                                                 const float* __restrict__ dinv, float* __restrict__ y) {
    __shared__ float Xl[64 * 68];
    __shared__ float Wl[64 * 64];
    const int tid = threadIdx.x;
    const int row0 = blockIdx.x * 64;
    const int tc = tid & 15, tr = tid >> 4;
    const int h0 = tc * 4;
    float4 acc[4];
#pragma unroll
    for (int rr = 0; rr < 4; ++rr) acc[rr] = make_float4(0.f, 0.f, 0.f, 0.f);

    for (int kc = 0; kc < KTOT; kc += 64) {
        __syncthreads();
        // stage X: 64 rows x 64 k (coalesced global, float4)
        for (int i = tid; i < 1024; i += 256) {
            int row = i >> 4, c4 = (i & 15) << 2;
            int gr = row0 + row;
            float4 v = make_float4(0.f, 0.f, 0.f, 0.f);
            if (gr < NN) v = *(const float4*)(x + (size_t)gr * KTOT + kc + c4);
            *(float4*)&Xl[row * 68 + c4] = v;
        }
        // stage W: 64 k x 64 h
        for (int i = tid; i < 1024; i += 256) {
            int k = i >> 4, h4 = (i & 15) << 2;
            *(float4*)&Wl[k * 64 + h4] = *(const float4*)(Wg + (size_t)(kc + k) * 64 + h4);
        }
        __syncthreads();
#pragma unroll 4
        for (int k = 0; k < 64; k += 4) {
            float4 w0 = *(float4*)&Wl[(k + 0) * 64 + h0];
            float4 w1 = *(float4*)&Wl[(k + 1) * 64 + h0];
            float4 w2 = *(float4*)&Wl[(k + 2) * 64 + h0];
            float4 w3 = *(float4*)&Wl[(k + 3) * 64 + h0];
#pragma unroll
            for (int rr = 0; rr < 4; ++rr) {
                float4 xv = *(float4*)&Xl[(rr * 16 + tr) * 68 + k];
                acc[rr].x += xv.x * w0.x + xv.y * w1.x + xv.z * w2.x + xv.w * w3.x;
                acc[rr].y += xv.x * w0.y + xv.y * w1.y + xv.z * w2.y + xv.w * w3.y;
                acc[rr].z += xv.x * w0.z + xv.y * w1.z + xv.z * w2.z + xv.w * w3.z;
                acc[rr].w += xv.x * w0.w + xv.y * w1.w + xv.z * w2.w + xv.w * w3.w;
            }
        }
    }
#pragma unroll
    for (int rr = 0; rr < 4; ++rr) {
        int r = row0 + rr * 16 + tr;
        if (r < NN) {
            float dv = dinv[r];
            float4 o = make_float4(acc[rr].x * dv, acc[rr].y * dv, acc[rr].z * dv, acc[rr].w * dv);
            *(float4*)(y + (size_t)r * 64 + h0) = o;
        }
    }
}

// ---------------- Aggregate ----------------
__global__ __launch_bounds__(256) void aggregate_kernel(const float* __restrict__ y, const int* __restrict__ row_ptr,
                                                        const int* __restrict__ col, const float* __restrict__ dinv,
                                                        const float* __restrict__ b, float* __restrict__ out, int relu) {
    int wv = threadIdx.x >> 6, h = threadIdx.x & 63;
    int d = blockIdx.x * 4 + wv;
    int s0 = row_ptr[d], s1 = row_ptr[d + 1];
    float acc = y[(size_t)d * 64 + h];  // self-loop
    int e = s0;
    for (; e + 4 <= s1; e += 4) {
        int a0 = col[e], a1 = col[e + 1], a2 = col[e + 2], a3 = col[e + 3];
        float v0 = y[(size_t)a0 * 64 + h];
        float v1 = y[(size_t)a1 * 64 + h];
        float v2 = y[(size_t)a2 * 64 + h];
        float v3 = y[(size_t)a3 * 64 + h];
        acc += (v0 + v1) + (v2 + v3);
    }
    for (; e < s1; ++e) acc += y[(size_t)col[e] * 64 + h];
    float r = dinv[d] * acc + b[h];
    if (relu) r = fmaxf(r, 0.f);
    out[(size_t)d * 64 + h] = r;
}

// ---------------- Tail ----------------
__global__ __launch_bounds__(256) void final_kernel(const float* __restrict__ h2, const float* __restrict__ W3,
                                                    const float* __restrict__ b3, float* __restrict__ out) {
    int tid = threadIdx.x;
    int wv = tid >> 6, lane = tid & 63;
    int d = blockIdx.x * 4 + wv;
    float v = h2[(size_t)d * 64 + lane];
    float sq = v * v;
#pragma unroll
    for (int off = 32; off > 0; off >>= 1) sq += __shfl_xor(sq, off);
    float inv = 1.0f / fmaxf(sqrtf(sq), 1e-12f);
    float hn = v * inv;
    out[1 + (size_t)NN * C_DIM + (size_t)d * 64 + lane] = hn;

    __shared__ float hl[4][64];
    hl[wv][lane] = hn;
    __syncthreads();

    int c = lane & 15, chunk = lane >> 4;
    float part = 0.f;
#pragma unroll
    for (int q = 0; q < 16; ++q) {
        int hh = chunk * 16 + q;
        part += hl[wv][hh] * W3[hh * 16 + c];
    }
    part += __shfl_xor(part, 16);
    part += __shfl_xor(part, 32);
    float logit = part + b3[c];

    float m = logit;
#pragma unroll
    for (int off = 8; off > 0; off >>= 1) m = fmaxf(m, __shfl_xor(m, off));
    float ex = __expf(logit - m);
    float se = ex;
#pragma unroll
    for (int off = 8; off > 0; off >>= 1) se += __shfl_xor(se, off);
    float pred = logit - m - __logf(se);
    if (lane < 16) out[1 + (size_t)d * 16 + lane] = pred;
}

__global__ __launch_bounds__(256) void loss_kernel(const float* __restrict__ out, const int* __restrict__ labels,
                                                   const int* __restrict__ train_idx, float* __restrict__ loss_ws) {
    int i = blockIdx.x * 256 + threadIdx.x;
    float v = 0.f;
    if (i < NT) {
        int idx = train_idx[i];
        int lab = labels[idx];
        v = -out[1 + (size_t)idx * 16 + lab];
    }
#pragma unroll
    for (int off = 32; off > 0; off >>= 1) v += __shfl_xor(v, off);
    __shared__ float ws4[4];
    int wv = threadIdx.x >> 6, lane = threadIdx.x & 63;
    if (lane == 0) ws4[wv] = v;
    __syncthreads();
    if (threadIdx.x == 0) atomicAdd(loss_ws, ws4[0] + ws4[1] + ws4[2] + ws4[3]);
}

__global__ void finalize_kernel(const float* __restrict__ loss_ws, float* __restrict__ out) {
    if (threadIdx.x == 0) out[0] = loss_ws[0] * (1.0f / NT);
}

// ---------------- launch ----------------

extern "C" void kernel_launch(void* const* d_in, const int* in_sizes, int n_in,
                              void* d_out, int out_size, void* d_ws, size_t ws_size,
                              hipStream_t stream) {
    const float* feats = (const float*)d_in[0];
    const float* W1 = (const float*)d_in[1];
    const float* b1 = (const float*)d_in[2];
    const float* W2 = (const float*)d_in[3];
    const float* b2 = (const float*)d_in[4];
    const float* W3 = (const float*)d_in[5];
    const float* b3 = (const float*)d_in[6];
    const int* edge_list = (const int*)d_in[7];
    const int* labels = (const int*)d_in[8];
    const int* train_idx = (const int*)d_in[9];
    float* out = (float*)d_out;

    char* w = (char*)d_ws;
    auto alloc = [&](size_t bytes) {
        char* p = w;
        w += (bytes + 255) & ~(size_t)255;
        return p;
    };
    int* cnt = (int*)alloc((size_t)NN * 4);
    int* cursor = (int*)alloc((size_t)NN * 4);
    int* row_ptr = (int*)alloc((size_t)(NN + 1) * 4);
    int* col = (int*)alloc((size_t)EE * 4);
    unsigned int* temp = (unsigned int*)alloc((size_t)EE * 4);
    float* dinv = (float*)alloc((size_t)NN * 4);
    float* bufA = (float*)alloc((size_t)NN * H_DIM * 4);
    float* bufB = (float*)alloc((size_t)NN * H_DIM * 4);
    float* loss_ws = (float*)alloc(4);
    int* bsum = (int*)alloc((size_t)NB * 4);
    int* bscan = (int*)alloc((size_t)(NB + 1) * 4);
    int* bucket_cursor = (int*)alloc((size_t)NBUK * 4);

    const int* srcp = edge_list;
    const int* dstp = edge_list + EE;

    zero_kernel<<<NB, 256, 0, stream>>>(cnt, loss_ws);
    hist_kernel<<<(EE + 255) / 256, 256, 0, stream>>>(dstp, cnt);
    scan_blocks<<<NB, 256, 0, stream>>>(cnt, row_ptr, bsum);
    scan_bsums<<<1, 256, 0, stream>>>(bsum, bscan);
    scan_finish<<<NB, 256, 0, stream>>>(cnt, bscan, row_ptr, cursor, dinv, bucket_cursor);
    multisplit_kernel<<<NCHUNK, 256, 0, stream>>>(srcp, dstp, bucket_cursor, temp);
    bucket_sort_kernel<<<NBUK, 256, 0, stream>>>(temp, row_ptr, cursor, col);

    const int GB = (NN + 63) / 64;  // 782
    // layer 0: feats @ W1, no relu
    gemm_tile<256><<<GB, 256, 0, stream>>>(feats, W1, dinv, bufA);
    aggregate_kernel<<<NN / 4, 256, 0, stream>>>(bufA, row_ptr, col, dinv, b1, bufB, 0);
    // layer 1: relu
    gemm_tile<64><<<GB, 256, 0, stream>>>(bufB, W2, dinv, bufA);
    aggregate_kernel<<<NN / 4, 256, 0, stream>>>(bufA, row_ptr, col, dinv, b2, bufB, 1);
    // layer 2: relu
    gemm_tile<64><<<GB, 256, 0, stream>>>(bufB, W2 + H_DIM * H_DIM, dinv, bufA);
    aggregate_kernel<<<NN / 4, 256, 0, stream>>>(bufA, row_ptr, col, dinv, b2 + H_DIM, bufB, 1);

    final_kernel<<<NN / 4, 256, 0, stream>>>(bufB, W3, b3, out);
    loss_kernel<<<(NT + 255) / 256, 256, 0, stream>>>(out, labels, train_idx, loss_ws);
    finalize_kernel<<<1, 64, 0, stream>>>(loss_ws, out);
}

// Round 5
// 414.838 us; speedup vs baseline: 1.7375x; 1.1608x over previous
//
#include <hip/hip_runtime.h>
#include <math.h>

#define NN 50000
#define EE 1600000
#define IN_DIM 256
#define H_DIM 64
#define C_DIM 16
#define NT 5000
#define NBUK 391  // ceil(NN/128)
#define CHUNK 8192
#define NCHUNK 196  // ceil(EE/CHUNK)
#define CAP 6144

// ---------------- CSR build ----------------

__global__ __launch_bounds__(256) void zero_kernel(int* __restrict__ bhist, float* __restrict__ loss_ws) {
    int i = blockIdx.x * 256 + threadIdx.x;
    if (i < NBUK) bhist[i] = 0;
    if (i == 0) *(int*)loss_ws = 0;
}

// Per-block LDS histogram of coarse buckets (dst>>7), one atomic flush per (block,bucket).
__global__ __launch_bounds__(256) void bucket_hist_kernel(const int* __restrict__ dst, int* __restrict__ bhist) {
    __shared__ int hist[NBUK];
    const int tid = threadIdx.x;
    const int base_e = blockIdx.x * CHUNK;
    for (int i = tid; i < NBUK; i += 256) hist[i] = 0;
    __syncthreads();
    for (int i = tid; i < CHUNK; i += 256) {
        int e = base_e + i;
        if (e < EE) atomicAdd(&hist[dst[e] >> 7], 1);
    }
    __syncthreads();
    for (int i = tid; i < NBUK; i += 256) {
        int c = hist[i];
        if (c) atomicAdd(&bhist[i], c);
    }
}

// Single tiny block: exclusive scan of 391 bucket counts -> bucket_base[0..NBUK], cursor copy.
__global__ __launch_bounds__(64) void bucket_scan_kernel(const int* __restrict__ bhist, int* __restrict__ bucket_base,
                                                         int* __restrict__ bucket_cursor) {
    int lane = threadIdx.x;
    int lc[7];
    int s = 0;
#pragma unroll
    for (int k = 0; k < 7; ++k) {
        int idx = lane * 7 + k;
        int c = (idx < NBUK) ? bhist[idx] : 0;
        lc[k] = c;
        s += c;
    }
    int v = s;
#pragma unroll
    for (int off = 1; off < 64; off <<= 1) {
        int u = __shfl_up(v, off);
        if (lane >= off) v += u;
    }
    int ex = v - s;
#pragma unroll
    for (int k = 0; k < 7; ++k) {
        int idx = lane * 7 + k;
        if (idx < NBUK) { bucket_base[idx] = ex; bucket_cursor[idx] = ex; }
        ex += lc[k];
    }
    if (lane == 63) bucket_base[NBUK] = v;  // == EE
}

// Multi-split by coarse bucket (dst>>7), LDS staging, coalesced flush to temp.
__global__ __launch_bounds__(256) void multisplit_kernel(const int* __restrict__ src, const int* __restrict__ dst,
                                                         int* __restrict__ bucket_cursor,
                                                         unsigned int* __restrict__ temp) {
    __shared__ int hist[NBUK];
    __shared__ int excl[NBUK + 1];
    __shared__ int offs[NBUK];
    __shared__ int delta[NBUK];
    __shared__ unsigned short bid[CHUNK];
    __shared__ unsigned int stag[CHUNK];

    const int tid = threadIdx.x;
    const int base_e = blockIdx.x * CHUNK;

    for (int i = tid; i < NBUK; i += 256) hist[i] = 0;
    __syncthreads();

    for (int i = tid; i < CHUNK; i += 256) {
        int e = base_e + i;
        if (e < EE) atomicAdd(&hist[dst[e] >> 7], 1);
    }
    __syncthreads();

    if (tid < 64) {
        int lane = tid;
        int lc[7];
        int s = 0;
#pragma unroll
        for (int k = 0; k < 7; ++k) {
            int idx = lane * 7 + k;
            int c = (idx < NBUK) ? hist[idx] : 0;
            lc[k] = c;
            s += c;
        }
        int v = s;
#pragma unroll
        for (int off = 1; off < 64; off <<= 1) {
            int u = __shfl_up(v, off);
            if (lane >= off) v += u;
        }
        int ex = v - s;
#pragma unroll
        for (int k = 0; k < 7; ++k) {
            int idx = lane * 7 + k;
            if (idx < NBUK) excl[idx] = ex;
            ex += lc[k];
        }
        if (lane == 63) excl[NBUK] = v;
    }
    __syncthreads();

    for (int b = tid; b < NBUK; b += 256) {
        int count = excl[b + 1] - excl[b];
        int gbase = atomicAdd(&bucket_cursor[b], count);
        delta[b] = gbase - excl[b];
        offs[b] = excl[b];
    }
    __syncthreads();

    for (int i = tid; i < CHUNK; i += 256) {
        int e = base_e + i;
        if (e < EE) {
            int d = dst[e];
            int s = src[e];
            int b = d >> 7;
            int rank = atomicAdd(&offs[b], 1);
            stag[rank] = (unsigned int)(((d & 127) << 16) | s);
            bid[rank] = (unsigned short)b;
        }
    }
    __syncthreads();

    int nval = excl[NBUK];
    for (int i = tid; i < nval; i += 256) {
        int b = bid[i];
        temp[delta[b] + i] = stag[i];
    }
}

// Per-bucket: count 128 per-dst in LDS, scan -> row_ptr + dinv, place into col (coalesced).
__global__ __launch_bounds__(256) void bucket_finalize_kernel(const unsigned int* __restrict__ temp,
                                                              const int* __restrict__ bucket_base,
                                                              int* __restrict__ row_ptr, float* __restrict__ dinv,
                                                              int* __restrict__ col) {
    __shared__ int cnt_l[128];
    __shared__ int exc[129];
    __shared__ int cur[128];
    __shared__ unsigned int stag[CAP];
    __shared__ int stag2[CAP];
    const int b = blockIdx.x;
    const int tid = threadIdx.x;
    const int d0 = b << 7;
    const int nd = (d0 + 128 < NN) ? 128 : (NN - d0);
    const int pos0 = bucket_base[b];
    const int M = bucket_base[b + 1] - pos0;
    const bool fit = (M <= CAP);

    for (int j = tid; j < 128; j += 256) cnt_l[j] = 0;
    __syncthreads();

    for (int i = tid; i < M; i += 256) {
        unsigned int v = temp[pos0 + i];
        if (fit) stag[i] = v;
        atomicAdd(&cnt_l[v >> 16], 1);
    }
    __syncthreads();

    // exclusive scan of 128 counts by wave 0 (2 per lane)
    if (tid < 64) {
        int c0 = cnt_l[2 * tid], c1 = cnt_l[2 * tid + 1];
        int s = c0 + c1;
        int v = s;
#pragma unroll
        for (int off = 1; off < 64; off <<= 1) {
            int u = __shfl_up(v, off);
            if (tid >= off) v += u;
        }
        int ex = v - s;
        exc[2 * tid] = ex;
        exc[2 * tid + 1] = ex + c0;
        if (tid == 63) exc[128] = v;  // == M
    }
    __syncthreads();

    if (tid < nd) {
        row_ptr[d0 + tid] = pos0 + exc[tid];
        dinv[d0 + tid] = rsqrtf((float)(cnt_l[tid] + 1));  // +1 self-loop
    }
    if (b == NBUK - 1 && tid == 0) row_ptr[NN] = pos0 + M;

    if (tid < 128) cur[tid] = exc[tid];
    __syncthreads();

    if (fit) {
        for (int i = tid; i < M; i += 256) {
            unsigned int v = stag[i];
            int r = atomicAdd(&cur[v >> 16], 1);
            stag2[r] = (int)(v & 0xFFFFu);
        }
        __syncthreads();
        for (int i = tid; i < M; i += 256) col[pos0 + i] = stag2[i];
    } else {
        for (int i = tid; i < M; i += 256) {
            unsigned int v = temp[pos0 + i];
            int r = atomicAdd(&cur[v >> 16], 1);
            col[pos0 + r] = (int)(v & 0xFFFFu);
        }
    }
}

// ---------------- GEMM: y[r][h] = (sum_k x[r][k] * W[k][h]) * dinv[r] ----------------
template <int KTOT>
__global__ __launch_bounds__(256) void gemm_tile(const float* __restrict__ x, const float* __restrict__ Wg,
                                                 const float* __restrict__ dinv, float* __restrict__ y) {
    __shared__ float Xl[64 * 68];
    __shared__ float Wl[64 * 64];
    const int tid = threadIdx.x;
    const int row0 = blockIdx.x * 64;
    const int tc = tid & 15, tr = tid >> 4;
    const int h0 = tc * 4;
    float4 acc[4];
#pragma unroll
    for (int rr = 0; rr < 4; ++rr) acc[rr] = make_float4(0.f, 0.f, 0.f, 0.f);

    for (int kc = 0; kc < KTOT; kc += 64) {
        __syncthreads();
        for (int i = tid; i < 1024; i += 256) {
            int row = i >> 4, c4 = (i & 15) << 2;
            int gr = row0 + row;
            float4 v = make_float4(0.f, 0.f, 0.f, 0.f);
            if (gr < NN) v = *(const float4*)(x + (size_t)gr * KTOT + kc + c4);
            *(float4*)&Xl[row * 68 + c4] = v;
        }
        for (int i = tid; i < 1024; i += 256) {
            int k = i >> 4, h4 = (i & 15) << 2;
            *(float4*)&Wl[k * 64 + h4] = *(const float4*)(Wg + (size_t)(kc + k) * 64 + h4);
        }
        __syncthreads();
#pragma unroll 4
        for (int k = 0; k < 64; k += 4) {
            float4 w0 = *(float4*)&Wl[(k + 0) * 64 + h0];
            float4 w1 = *(float4*)&Wl[(k + 1) * 64 + h0];
            float4 w2 = *(float4*)&Wl[(k + 2) * 64 + h0];
            float4 w3 = *(float4*)&Wl[(k + 3) * 64 + h0];
#pragma unroll
            for (int rr = 0; rr < 4; ++rr) {
                float4 xv = *(float4*)&Xl[(rr * 16 + tr) * 68 + k];
                acc[rr].x += xv.x * w0.x + xv.y * w1.x + xv.z * w2.x + xv.w * w3.x;
                acc[rr].y += xv.x * w0.y + xv.y * w1.y + xv.z * w2.y + xv.w * w3.y;
                acc[rr].z += xv.x * w0.z + xv.y * w1.z + xv.z * w2.z + xv.w * w3.z;
                acc[rr].w += xv.x * w0.w + xv.y * w1.w + xv.z * w2.w + xv.w * w3.w;
            }
        }
    }
#pragma unroll
    for (int rr = 0; rr < 4; ++rr) {
        int r = row0 + rr * 16 + tr;
        if (r < NN) {
            float dv = dinv[r];
            float4 o = make_float4(acc[rr].x * dv, acc[rr].y * dv, acc[rr].z * dv, acc[rr].w * dv);
            *(float4*)(y + (size_t)r * 64 + h0) = o;
        }
    }
}

// ---------------- Aggregate ----------------
__global__ __launch_bounds__(256) void aggregate_kernel(const float* __restrict__ y, const int* __restrict__ row_ptr,
                                                        const int* __restrict__ col, const float* __restrict__ dinv,
                                                        const float* __restrict__ b, float* __restrict__ out, int relu) {
    int wv = threadIdx.x >> 6, h = threadIdx.x & 63;
    int d = blockIdx.x * 4 + wv;
    int s0 = row_ptr[d], s1 = row_ptr[d + 1];
    float acc = y[(size_t)d * 64 + h];  // self-loop
    int e = s0;
    for (; e + 4 <= s1; e += 4) {
        int a0 = col[e], a1 = col[e + 1], a2 = col[e + 2], a3 = col[e + 3];
        float v0 = y[(size_t)a0 * 64 + h];
        float v1 = y[(size_t)a1 * 64 + h];
        float v2 = y[(size_t)a2 * 64 + h];
        float v3 = y[(size_t)a3 * 64 + h];
        acc += (v0 + v1) + (v2 + v3);
    }
    for (; e < s1; ++e) acc += y[(size_t)col[e] * 64 + h];
    float r = dinv[d] * acc + b[h];
    if (relu) r = fmaxf(r, 0.f);
    out[(size_t)d * 64 + h] = r;
}

// ---------------- Tail ----------------
__global__ __launch_bounds__(256) void final_kernel(const float* __restrict__ h2, const float* __restrict__ W3,
                                                    const float* __restrict__ b3, float* __restrict__ out) {
    int tid = threadIdx.x;
    int wv = tid >> 6, lane = tid & 63;
    int d = blockIdx.x * 4 + wv;
    float v = h2[(size_t)d * 64 + lane];
    float sq = v * v;
#pragma unroll
    for (int off = 32; off > 0; off >>= 1) sq += __shfl_xor(sq, off);
    float inv = 1.0f / fmaxf(sqrtf(sq), 1e-12f);
    float hn = v * inv;
    out[1 + (size_t)NN * C_DIM + (size_t)d * 64 + lane] = hn;

    __shared__ float hl[4][64];
    hl[wv][lane] = hn;
    __syncthreads();

    int c = lane & 15, chunk = lane >> 4;
    float part = 0.f;
#pragma unroll
    for (int q = 0; q < 16; ++q) {
        int hh = chunk * 16 + q;
        part += hl[wv][hh] * W3[hh * 16 + c];
    }
    part += __shfl_xor(part, 16);
    part += __shfl_xor(part, 32);
    float logit = part + b3[c];

    float m = logit;
#pragma unroll
    for (int off = 8; off > 0; off >>= 1) m = fmaxf(m, __shfl_xor(m, off));
    float ex = __expf(logit - m);
    float se = ex;
#pragma unroll
    for (int off = 8; off > 0; off >>= 1) se += __shfl_xor(se, off);
    float pred = logit - m - __logf(se);
    if (lane < 16) out[1 + (size_t)d * 16 + lane] = pred;
}

__global__ __launch_bounds__(256) void loss_kernel(const float* __restrict__ out, const int* __restrict__ labels,
                                                   const int* __restrict__ train_idx, float* __restrict__ loss_ws) {
    int i = blockIdx.x * 256 + threadIdx.x;
    float v = 0.f;
    if (i < NT) {
        int idx = train_idx[i];
        int lab = labels[idx];
        v = -out[1 + (size_t)idx * 16 + lab];
    }
#pragma unroll
    for (int off = 32; off > 0; off >>= 1) v += __shfl_xor(v, off);
    __shared__ float ws4[4];
    int wv = threadIdx.x >> 6, lane = threadIdx.x & 63;
    if (lane == 0) ws4[wv] = v;
    __syncthreads();
    if (threadIdx.x == 0) atomicAdd(loss_ws, ws4[0] + ws4[1] + ws4[2] + ws4[3]);
}

__global__ void finalize_kernel(const float* __restrict__ loss_ws, float* __restrict__ out) {
    if (threadIdx.x == 0) out[0] = loss_ws[0] * (1.0f / NT);
}

// ---------------- launch ----------------

extern "C" void kernel_launch(void* const* d_in, const int* in_sizes, int n_in,
                              void* d_out, int out_size, void* d_ws, size_t ws_size,
                              hipStream_t stream) {
    const float* feats = (const float*)d_in[0];
    const float* W1 = (const float*)d_in[1];
    const float* b1 = (const float*)d_in[2];
    const float* W2 = (const float*)d_in[3];
    const float* b2 = (const float*)d_in[4];
    const float* W3 = (const float*)d_in[5];
    const float* b3 = (const float*)d_in[6];
    const int* edge_list = (const int*)d_in[7];
    const int* labels = (const int*)d_in[8];
    const int* train_idx = (const int*)d_in[9];
    float* out = (float*)d_out;

    char* w = (char*)d_ws;
    auto alloc = [&](size_t bytes) {
        char* p = w;
        w += (bytes + 255) & ~(size_t)255;
        return p;
    };
    int* row_ptr = (int*)alloc((size_t)(NN + 1) * 4);
    int* col = (int*)alloc((size_t)EE * 4);
    unsigned int* temp = (unsigned int*)alloc((size_t)EE * 4);
    float* dinv = (float*)alloc((size_t)NN * 4);
    float* bufA = (float*)alloc((size_t)NN * H_DIM * 4);
    float* bufB = (float*)alloc((size_t)NN * H_DIM * 4);
    float* loss_ws = (float*)alloc(4);
    int* bhist = (int*)alloc((size_t)NBUK * 4);
    int* bucket_base = (int*)alloc((size_t)(NBUK + 1) * 4);
    int* bucket_cursor = (int*)alloc((size_t)NBUK * 4);

    const int* srcp = edge_list;
    const int* dstp = edge_list + EE;

    zero_kernel<<<2, 256, 0, stream>>>(bhist, loss_ws);
    bucket_hist_kernel<<<NCHUNK, 256, 0, stream>>>(dstp, bhist);
    bucket_scan_kernel<<<1, 64, 0, stream>>>(bhist, bucket_base, bucket_cursor);
    multisplit_kernel<<<NCHUNK, 256, 0, stream>>>(srcp, dstp, bucket_cursor, temp);
    bucket_finalize_kernel<<<NBUK, 256, 0, stream>>>(temp, bucket_base, row_ptr, dinv, col);

    const int GB = (NN + 63) / 64;  // 782
    // layer 0: feats @ W1, no relu
    gemm_tile<256><<<GB, 256, 0, stream>>>(feats, W1, dinv, bufA);
    aggregate_kernel<<<NN / 4, 256, 0, stream>>>(bufA, row_ptr, col, dinv, b1, bufB, 0);
    // layer 1: relu
    gemm_tile<64><<<GB, 256, 0, stream>>>(bufB, W2, dinv, bufA);
    aggregate_kernel<<<NN / 4, 256, 0, stream>>>(bufA, row_ptr, col, dinv, b2, bufB, 1);
    // layer 2: relu
    gemm_tile<64><<<GB, 256, 0, stream>>>(bufB, W2 + H_DIM * H_DIM, dinv, bufA);
    aggregate_kernel<<<NN / 4, 256, 0, stream>>>(bufA, row_ptr, col, dinv, b2 + H_DIM, bufB, 1);

    final_kernel<<<NN / 4, 256, 0, stream>>>(bufB, W3, b3, out);
    loss_kernel<<<(NT + 255) / 256, 256, 0, stream>>>(out, labels, train_idx, loss_ws);
    finalize_kernel<<<1, 64, 0, stream>>>(loss_ws, out);
}

// Round 6
// 372.999 us; speedup vs baseline: 1.9324x; 1.1122x over previous
//
#include <hip/hip_runtime.h>
#include <math.h>

#define NN 50000
#define EE 1600000
#define IN_DIM 256
#define H_DIM 64
#define C_DIM 16
#define NT 5000
#define NBUK 391  // ceil(NN/128)
#define CHUNK 8192
#define NCHUNK 196  // ceil(EE/CHUNK)
#define CAP 6144

__device__ __forceinline__ unsigned short f2bf(float f) {
    unsigned int u = __float_as_uint(f);
    u = (u + 0x7FFFu + ((u >> 16) & 1u)) >> 16;  // round-to-nearest-even
    return (unsigned short)u;
}
__device__ __forceinline__ float bf2f(unsigned short s) {
    return __uint_as_float(((unsigned int)s) << 16);
}

// ---------------- CSR build ----------------

__global__ __launch_bounds__(256) void zero_kernel(int* __restrict__ bhist, float* __restrict__ loss_ws) {
    int i = blockIdx.x * 256 + threadIdx.x;
    if (i < NBUK) bhist[i] = 0;
    if (i == 0) *(int*)loss_ws = 0;
}

__global__ __launch_bounds__(256) void bucket_hist_kernel(const int* __restrict__ dst, int* __restrict__ bhist) {
    __shared__ int hist[NBUK];
    const int tid = threadIdx.x;
    const int base_e = blockIdx.x * CHUNK;
    for (int i = tid; i < NBUK; i += 256) hist[i] = 0;
    __syncthreads();
    for (int i = tid; i < CHUNK; i += 256) {
        int e = base_e + i;
        if (e < EE) atomicAdd(&hist[dst[e] >> 7], 1);
    }
    __syncthreads();
    for (int i = tid; i < NBUK; i += 256) {
        int c = hist[i];
        if (c) atomicAdd(&bhist[i], c);
    }
}

__global__ __launch_bounds__(64) void bucket_scan_kernel(const int* __restrict__ bhist, int* __restrict__ bucket_base,
                                                         int* __restrict__ bucket_cursor) {
    int lane = threadIdx.x;
    int lc[7];
    int s = 0;
#pragma unroll
    for (int k = 0; k < 7; ++k) {
        int idx = lane * 7 + k;
        int c = (idx < NBUK) ? bhist[idx] : 0;
        lc[k] = c;
        s += c;
    }
    int v = s;
#pragma unroll
    for (int off = 1; off < 64; off <<= 1) {
        int u = __shfl_up(v, off);
        if (lane >= off) v += u;
    }
    int ex = v - s;
#pragma unroll
    for (int k = 0; k < 7; ++k) {
        int idx = lane * 7 + k;
        if (idx < NBUK) { bucket_base[idx] = ex; bucket_cursor[idx] = ex; }
        ex += lc[k];
    }
    if (lane == 63) bucket_base[NBUK] = v;  // == EE
}

__global__ __launch_bounds__(256) void multisplit_kernel(const int* __restrict__ src, const int* __restrict__ dst,
                                                         int* __restrict__ bucket_cursor,
                                                         unsigned int* __restrict__ temp) {
    __shared__ int hist[NBUK];
    __shared__ int excl[NBUK + 1];
    __shared__ int offs[NBUK];
    __shared__ int delta[NBUK];
    __shared__ unsigned short bid[CHUNK];
    __shared__ unsigned int stag[CHUNK];

    const int tid = threadIdx.x;
    const int base_e = blockIdx.x * CHUNK;

    for (int i = tid; i < NBUK; i += 256) hist[i] = 0;
    __syncthreads();

    for (int i = tid; i < CHUNK; i += 256) {
        int e = base_e + i;
        if (e < EE) atomicAdd(&hist[dst[e] >> 7], 1);
    }
    __syncthreads();

    if (tid < 64) {
        int lane = tid;
        int lc[7];
        int s = 0;
#pragma unroll
        for (int k = 0; k < 7; ++k) {
            int idx = lane * 7 + k;
            int c = (idx < NBUK) ? hist[idx] : 0;
            lc[k] = c;
            s += c;
        }
        int v = s;
#pragma unroll
        for (int off = 1; off < 64; off <<= 1) {
            int u = __shfl_up(v, off);
            if (lane >= off) v += u;
        }
        int ex = v - s;
#pragma unroll
        for (int k = 0; k < 7; ++k) {
            int idx = lane * 7 + k;
            if (idx < NBUK) excl[idx] = ex;
            ex += lc[k];
        }
        if (lane == 63) excl[NBUK] = v;
    }
    __syncthreads();

    for (int b = tid; b < NBUK; b += 256) {
        int count = excl[b + 1] - excl[b];
        int gbase = atomicAdd(&bucket_cursor[b], count);
        delta[b] = gbase - excl[b];
        offs[b] = excl[b];
    }
    __syncthreads();

    for (int i = tid; i < CHUNK; i += 256) {
        int e = base_e + i;
        if (e < EE) {
            int d = dst[e];
            int s = src[e];
            int b = d >> 7;
            int rank = atomicAdd(&offs[b], 1);
            stag[rank] = (unsigned int)(((d & 127) << 16) | s);
            bid[rank] = (unsigned short)b;
        }
    }
    __syncthreads();

    int nval = excl[NBUK];
    for (int i = tid; i < nval; i += 256) {
        int b = bid[i];
        temp[delta[b] + i] = stag[i];
    }
}

__global__ __launch_bounds__(256) void bucket_finalize_kernel(const unsigned int* __restrict__ temp,
                                                              const int* __restrict__ bucket_base,
                                                              int* __restrict__ row_ptr, float* __restrict__ dinv,
                                                              int* __restrict__ col) {
    __shared__ int cnt_l[128];
    __shared__ int exc[129];
    __shared__ int cur[128];
    __shared__ unsigned int stag[CAP];
    __shared__ int stag2[CAP];
    const int b = blockIdx.x;
    const int tid = threadIdx.x;
    const int d0 = b << 7;
    const int nd = (d0 + 128 < NN) ? 128 : (NN - d0);
    const int pos0 = bucket_base[b];
    const int M = bucket_base[b + 1] - pos0;
    const bool fit = (M <= CAP);

    for (int j = tid; j < 128; j += 256) cnt_l[j] = 0;
    __syncthreads();

    for (int i = tid; i < M; i += 256) {
        unsigned int v = temp[pos0 + i];
        if (fit) stag[i] = v;
        atomicAdd(&cnt_l[v >> 16], 1);
    }
    __syncthreads();

    if (tid < 64) {
        int c0 = cnt_l[2 * tid], c1 = cnt_l[2 * tid + 1];
        int s = c0 + c1;
        int v = s;
#pragma unroll
        for (int off = 1; off < 64; off <<= 1) {
            int u = __shfl_up(v, off);
            if (tid >= off) v += u;
        }
        int ex = v - s;
        exc[2 * tid] = ex;
        exc[2 * tid + 1] = ex + c0;
        if (tid == 63) exc[128] = v;  // == M
    }
    __syncthreads();

    if (tid < nd) {
        row_ptr[d0 + tid] = pos0 + exc[tid];
        dinv[d0 + tid] = rsqrtf((float)(cnt_l[tid] + 1));  // +1 self-loop
    }
    if (b == NBUK - 1 && tid == 0) row_ptr[NN] = pos0 + M;

    if (tid < 128) cur[tid] = exc[tid];
    __syncthreads();

    if (fit) {
        for (int i = tid; i < M; i += 256) {
            unsigned int v = stag[i];
            int r = atomicAdd(&cur[v >> 16], 1);
            stag2[r] = (int)(v & 0xFFFFu);
        }
        __syncthreads();
        for (int i = tid; i < M; i += 256) col[pos0 + i] = stag2[i];
    } else {
        for (int i = tid; i < M; i += 256) {
            unsigned int v = temp[pos0 + i];
            int r = atomicAdd(&cur[v >> 16], 1);
            col[pos0 + r] = (int)(v & 0xFFFFu);
        }
    }
}

// ---------------- GEMM: y[r][h] = bf16( (sum_k x[r][k] * W[k][h]) * dinv[r] ) ----------------
template <int KTOT>
__global__ __launch_bounds__(256) void gemm_tile(const float* __restrict__ x, const float* __restrict__ Wg,
                                                 const float* __restrict__ dinv, unsigned short* __restrict__ y) {
    __shared__ float Xl[64 * 68];
    __shared__ float Wl[64 * 64];
    const int tid = threadIdx.x;
    const int row0 = blockIdx.x * 64;
    const int tc = tid & 15, tr = tid >> 4;
    const int h0 = tc * 4;
    float4 acc[4];
#pragma unroll
    for (int rr = 0; rr < 4; ++rr) acc[rr] = make_float4(0.f, 0.f, 0.f, 0.f);

    for (int kc = 0; kc < KTOT; kc += 64) {
        __syncthreads();
        for (int i = tid; i < 1024; i += 256) {
            int row = i >> 4, c4 = (i & 15) << 2;
            int gr = row0 + row;
            float4 v = make_float4(0.f, 0.f, 0.f, 0.f);
            if (gr < NN) v = *(const float4*)(x + (size_t)gr * KTOT + kc + c4);
            *(float4*)&Xl[row * 68 + c4] = v;
        }
        for (int i = tid; i < 1024; i += 256) {
            int k = i >> 4, h4 = (i & 15) << 2;
            *(float4*)&Wl[k * 64 + h4] = *(const float4*)(Wg + (size_t)(kc + k) * 64 + h4);
        }
        __syncthreads();
#pragma unroll 4
        for (int k = 0; k < 64; k += 4) {
            float4 w0 = *(float4*)&Wl[(k + 0) * 64 + h0];
            float4 w1 = *(float4*)&Wl[(k + 1) * 64 + h0];
            float4 w2 = *(float4*)&Wl[(k + 2) * 64 + h0];
            float4 w3 = *(float4*)&Wl[(k + 3) * 64 + h0];
#pragma unroll
            for (int rr = 0; rr < 4; ++rr) {
                float4 xv = *(float4*)&Xl[(rr * 16 + tr) * 68 + k];
                acc[rr].x += xv.x * w0.x + xv.y * w1.x + xv.z * w2.x + xv.w * w3.x;
                acc[rr].y += xv.x * w0.y + xv.y * w1.y + xv.z * w2.y + xv.w * w3.y;
                acc[rr].z += xv.x * w0.z + xv.y * w1.z + xv.z * w2.z + xv.w * w3.z;
                acc[rr].w += xv.x * w0.w + xv.y * w1.w + xv.z * w2.w + xv.w * w3.w;
            }
        }
    }
#pragma unroll
    for (int rr = 0; rr < 4; ++rr) {
        int r = row0 + rr * 16 + tr;
        if (r < NN) {
            float dv = dinv[r];
            ushort4 o;
            o.x = f2bf(acc[rr].x * dv);
            o.y = f2bf(acc[rr].y * dv);
            o.z = f2bf(acc[rr].z * dv);
            o.w = f2bf(acc[rr].w * dv);
            *(ushort4*)(y + (size_t)r * 64 + h0) = o;
        }
    }
}

// ---------------- Aggregate: out[d][h] = act(dinv[d]*(y[d][h] + sum_in y[src][h]) + b[h]) ----------------
__global__ __launch_bounds__(256) void aggregate_kernel(const unsigned short* __restrict__ y,
                                                        const int* __restrict__ row_ptr,
                                                        const int* __restrict__ col, const float* __restrict__ dinv,
                                                        const float* __restrict__ b, float* __restrict__ out, int relu) {
    int wv = threadIdx.x >> 6, h = threadIdx.x & 63;
    int d = blockIdx.x * 4 + wv;
    int s0 = row_ptr[d], s1 = row_ptr[d + 1];
    float acc0 = bf2f(y[(size_t)d * 64 + h]);  // self-loop
    float acc1 = 0.f, acc2 = 0.f, acc3 = 0.f;
    int e = s0;
    for (; e + 8 <= s1; e += 8) {
        int a0 = col[e], a1 = col[e + 1], a2 = col[e + 2], a3 = col[e + 3];
        int a4 = col[e + 4], a5 = col[e + 5], a6 = col[e + 6], a7 = col[e + 7];
        float v0 = bf2f(y[(size_t)a0 * 64 + h]);
        float v1 = bf2f(y[(size_t)a1 * 64 + h]);
        float v2 = bf2f(y[(size_t)a2 * 64 + h]);
        float v3 = bf2f(y[(size_t)a3 * 64 + h]);
        float v4 = bf2f(y[(size_t)a4 * 64 + h]);
        float v5 = bf2f(y[(size_t)a5 * 64 + h]);
        float v6 = bf2f(y[(size_t)a6 * 64 + h]);
        float v7 = bf2f(y[(size_t)a7 * 64 + h]);
        acc0 += v0; acc1 += v1; acc2 += v2; acc3 += v3;
        acc0 += v4; acc1 += v5; acc2 += v6; acc3 += v7;
    }
    for (; e < s1; ++e) acc0 += bf2f(y[(size_t)col[e] * 64 + h]);
    float acc = (acc0 + acc1) + (acc2 + acc3);
    float r = dinv[d] * acc + b[h];
    if (relu) r = fmaxf(r, 0.f);
    out[(size_t)d * 64 + h] = r;
}

// ---------------- Tail ----------------
__global__ __launch_bounds__(256) void final_kernel(const float* __restrict__ h2, const float* __restrict__ W3,
                                                    const float* __restrict__ b3, float* __restrict__ out) {
    int tid = threadIdx.x;
    int wv = tid >> 6, lane = tid & 63;
    int d = blockIdx.x * 4 + wv;
    float v = h2[(size_t)d * 64 + lane];
    float sq = v * v;
#pragma unroll
    for (int off = 32; off > 0; off >>= 1) sq += __shfl_xor(sq, off);
    float inv = 1.0f / fmaxf(sqrtf(sq), 1e-12f);
    float hn = v * inv;
    out[1 + (size_t)NN * C_DIM + (size_t)d * 64 + lane] = hn;

    __shared__ float hl[4][64];
    hl[wv][lane] = hn;
    __syncthreads();

    int c = lane & 15, chunk = lane >> 4;
    float part = 0.f;
#pragma unroll
    for (int q = 0; q < 16; ++q) {
        int hh = chunk * 16 + q;
        part += hl[wv][hh] * W3[hh * 16 + c];
    }
    part += __shfl_xor(part, 16);
    part += __shfl_xor(part, 32);
    float logit = part + b3[c];

    float m = logit;
#pragma unroll
    for (int off = 8; off > 0; off >>= 1) m = fmaxf(m, __shfl_xor(m, off));
    float ex = __expf(logit - m);
    float se = ex;
#pragma unroll
    for (int off = 8; off > 0; off >>= 1) se += __shfl_xor(se, off);
    float pred = logit - m - __logf(se);
    if (lane < 16) out[1 + (size_t)d * 16 + lane] = pred;
}

__global__ __launch_bounds__(256) void loss_kernel(const float* __restrict__ out, const int* __restrict__ labels,
                                                   const int* __restrict__ train_idx, float* __restrict__ loss_ws) {
    int i = blockIdx.x * 256 + threadIdx.x;
    float v = 0.f;
    if (i < NT) {
        int idx = train_idx[i];
        int lab = labels[idx];
        v = -out[1 + (size_t)idx * 16 + lab];
    }
#pragma unroll
    for (int off = 32; off > 0; off >>= 1) v += __shfl_xor(v, off);
    __shared__ float ws4[4];
    int wv = threadIdx.x >> 6, lane = threadIdx.x & 63;
    if (lane == 0) ws4[wv] = v;
    __syncthreads();
    if (threadIdx.x == 0) atomicAdd(loss_ws, ws4[0] + ws4[1] + ws4[2] + ws4[3]);
}

__global__ void finalize_kernel(const float* __restrict__ loss_ws, float* __restrict__ out) {
    if (threadIdx.x == 0) out[0] = loss_ws[0] * (1.0f / NT);
}

// ---------------- launch ----------------

extern "C" void kernel_launch(void* const* d_in, const int* in_sizes, int n_in,
                              void* d_out, int out_size, void* d_ws, size_t ws_size,
                              hipStream_t stream) {
    const float* feats = (const float*)d_in[0];
    const float* W1 = (const float*)d_in[1];
    const float* b1 = (const float*)d_in[2];
    const float* W2 = (const float*)d_in[3];
    const float* b2 = (const float*)d_in[4];
    const float* W3 = (const float*)d_in[5];
    const float* b3 = (const float*)d_in[6];
    const int* edge_list = (const int*)d_in[7];
    const int* labels = (const int*)d_in[8];
    const int* train_idx = (const int*)d_in[9];
    float* out = (float*)d_out;

    char* w = (char*)d_ws;
    auto alloc = [&](size_t bytes) {
        char* p = w;
        w += (bytes + 255) & ~(size_t)255;
        return p;
    };
    int* row_ptr = (int*)alloc((size_t)(NN + 1) * 4);
    int* col = (int*)alloc((size_t)EE * 4);
    unsigned int* temp = (unsigned int*)alloc((size_t)EE * 4);
    float* dinv = (float*)alloc((size_t)NN * 4);
    unsigned short* yb = (unsigned short*)alloc((size_t)NN * H_DIM * 2);
    float* bufB = (float*)alloc((size_t)NN * H_DIM * 4);
    float* loss_ws = (float*)alloc(4);
    int* bhist = (int*)alloc((size_t)NBUK * 4);
    int* bucket_base = (int*)alloc((size_t)(NBUK + 1) * 4);
    int* bucket_cursor = (int*)alloc((size_t)NBUK * 4);

    const int* srcp = edge_list;
    const int* dstp = edge_list + EE;

    zero_kernel<<<2, 256, 0, stream>>>(bhist, loss_ws);
    bucket_hist_kernel<<<NCHUNK, 256, 0, stream>>>(dstp, bhist);
    bucket_scan_kernel<<<1, 64, 0, stream>>>(bhist, bucket_base, bucket_cursor);
    multisplit_kernel<<<NCHUNK, 256, 0, stream>>>(srcp, dstp, bucket_cursor, temp);
    bucket_finalize_kernel<<<NBUK, 256, 0, stream>>>(temp, bucket_base, row_ptr, dinv, col);

    const int GB = (NN + 63) / 64;  // 782
    // layer 0: feats @ W1, no relu
    gemm_tile<256><<<GB, 256, 0, stream>>>(feats, W1, dinv, yb);
    aggregate_kernel<<<NN / 4, 256, 0, stream>>>(yb, row_ptr, col, dinv, b1, bufB, 0);
    // layer 1: relu
    gemm_tile<64><<<GB, 256, 0, stream>>>(bufB, W2, dinv, yb);
    aggregate_kernel<<<NN / 4, 256, 0, stream>>>(yb, row_ptr, col, dinv, b2, bufB, 1);
    // layer 2: relu
    gemm_tile<64><<<GB, 256, 0, stream>>>(bufB, W2 + H_DIM * H_DIM, dinv, yb);
    aggregate_kernel<<<NN / 4, 256, 0, stream>>>(yb, row_ptr, col, dinv, b2 + H_DIM, bufB, 1);

    final_kernel<<<NN / 4, 256, 0, stream>>>(bufB, W3, b3, out);
    loss_kernel<<<(NT + 255) / 256, 256, 0, stream>>>(out, labels, train_idx, loss_ws);
    finalize_kernel<<<1, 64, 0, stream>>>(loss_ws, out);
}

// Round 7
// 323.581 us; speedup vs baseline: 2.2275x; 1.1527x over previous
//
#include <hip/hip_runtime.h>
#include <math.h>

#define NN 50000
#define EE 1600000
#define IN_DIM 256
#define H_DIM 64
#define C_DIM 16
#define NT 5000
#define NBUK 391  // ceil(NN/128)
#define CHUNK 8192
#define NCHUNK 196  // ceil(EE/CHUNK)
#define CAP 6144

__device__ __forceinline__ unsigned short f2bf(float f) {
    unsigned int u = __float_as_uint(f);
    u = (u + 0x7FFFu + ((u >> 16) & 1u)) >> 16;  // round-to-nearest-even
    return (unsigned short)u;
}
__device__ __forceinline__ float bf2f(unsigned short s) {
    return __uint_as_float(((unsigned int)s) << 16);
}

// ---------------- CSR build ----------------

__global__ __launch_bounds__(256) void zero_kernel(int* __restrict__ bhist, float* __restrict__ loss_ws) {
    int i = blockIdx.x * 256 + threadIdx.x;
    if (i < NBUK) bhist[i] = 0;
    if (i == 0) *(int*)loss_ws = 0;
}

__global__ __launch_bounds__(256) void bucket_hist_kernel(const int* __restrict__ dst, int* __restrict__ bhist) {
    __shared__ int hist[NBUK];
    const int tid = threadIdx.x;
    const int base_e = blockIdx.x * CHUNK;
    for (int i = tid; i < NBUK; i += 256) hist[i] = 0;
    __syncthreads();
    for (int i = tid; i < CHUNK; i += 256) {
        int e = base_e + i;
        if (e < EE) atomicAdd(&hist[dst[e] >> 7], 1);
    }
    __syncthreads();
    for (int i = tid; i < NBUK; i += 256) {
        int c = hist[i];
        if (c) atomicAdd(&bhist[i], c);
    }
}

__global__ __launch_bounds__(64) void bucket_scan_kernel(const int* __restrict__ bhist, int* __restrict__ bucket_base,
                                                         int* __restrict__ bucket_cursor) {
    int lane = threadIdx.x;
    int lc[7];
    int s = 0;
#pragma unroll
    for (int k = 0; k < 7; ++k) {
        int idx = lane * 7 + k;
        int c = (idx < NBUK) ? bhist[idx] : 0;
        lc[k] = c;
        s += c;
    }
    int v = s;
#pragma unroll
    for (int off = 1; off < 64; off <<= 1) {
        int u = __shfl_up(v, off);
        if (lane >= off) v += u;
    }
    int ex = v - s;
#pragma unroll
    for (int k = 0; k < 7; ++k) {
        int idx = lane * 7 + k;
        if (idx < NBUK) { bucket_base[idx] = ex; bucket_cursor[idx] = ex; }
        ex += lc[k];
    }
    if (lane == 63) bucket_base[NBUK] = v;  // == EE
}

__global__ __launch_bounds__(256) void multisplit_kernel(const int* __restrict__ src, const int* __restrict__ dst,
                                                         int* __restrict__ bucket_cursor,
                                                         unsigned int* __restrict__ temp) {
    __shared__ int hist[NBUK];
    __shared__ int excl[NBUK + 1];
    __shared__ int offs[NBUK];
    __shared__ int delta[NBUK];
    __shared__ unsigned short bid[CHUNK];
    __shared__ unsigned int stag[CHUNK];

    const int tid = threadIdx.x;
    const int base_e = blockIdx.x * CHUNK;

    for (int i = tid; i < NBUK; i += 256) hist[i] = 0;
    __syncthreads();

    for (int i = tid; i < CHUNK; i += 256) {
        int e = base_e + i;
        if (e < EE) atomicAdd(&hist[dst[e] >> 7], 1);
    }
    __syncthreads();

    if (tid < 64) {
        int lane = tid;
        int lc[7];
        int s = 0;
#pragma unroll
        for (int k = 0; k < 7; ++k) {
            int idx = lane * 7 + k;
            int c = (idx < NBUK) ? hist[idx] : 0;
            lc[k] = c;
            s += c;
        }
        int v = s;
#pragma unroll
        for (int off = 1; off < 64; off <<= 1) {
            int u = __shfl_up(v, off);
            if (lane >= off) v += u;
        }
        int ex = v - s;
#pragma unroll
        for (int k = 0; k < 7; ++k) {
            int idx = lane * 7 + k;
            if (idx < NBUK) excl[idx] = ex;
            ex += lc[k];
        }
        if (lane == 63) excl[NBUK] = v;
    }
    __syncthreads();

    for (int b = tid; b < NBUK; b += 256) {
        int count = excl[b + 1] - excl[b];
        int gbase = atomicAdd(&bucket_cursor[b], count);
        delta[b] = gbase - excl[b];
        offs[b] = excl[b];
    }
    __syncthreads();

    for (int i = tid; i < CHUNK; i += 256) {
        int e = base_e + i;
        if (e < EE) {
            int d = dst[e];
            int s = src[e];
            int b = d >> 7;
            int rank = atomicAdd(&offs[b], 1);
            stag[rank] = (unsigned int)(((d & 127) << 16) | s);
            bid[rank] = (unsigned short)b;
        }
    }
    __syncthreads();

    int nval = excl[NBUK];
    for (int i = tid; i < nval; i += 256) {
        int b = bid[i];
        temp[delta[b] + i] = stag[i];
    }
}

__global__ __launch_bounds__(256) void bucket_finalize_kernel(const unsigned int* __restrict__ temp,
                                                              const int* __restrict__ bucket_base,
                                                              int* __restrict__ row_ptr, float* __restrict__ dinv,
                                                              int* __restrict__ col) {
    __shared__ int cnt_l[128];
    __shared__ int exc[129];
    __shared__ int cur[128];
    __shared__ unsigned int stag[CAP];
    __shared__ int stag2[CAP];
    const int b = blockIdx.x;
    const int tid = threadIdx.x;
    const int d0 = b << 7;
    const int nd = (d0 + 128 < NN) ? 128 : (NN - d0);
    const int pos0 = bucket_base[b];
    const int M = bucket_base[b + 1] - pos0;
    const bool fit = (M <= CAP);

    for (int j = tid; j < 128; j += 256) cnt_l[j] = 0;
    __syncthreads();

    for (int i = tid; i < M; i += 256) {
        unsigned int v = temp[pos0 + i];
        if (fit) stag[i] = v;
        atomicAdd(&cnt_l[v >> 16], 1);
    }
    __syncthreads();

    if (tid < 64) {
        int c0 = cnt_l[2 * tid], c1 = cnt_l[2 * tid + 1];
        int s = c0 + c1;
        int v = s;
#pragma unroll
        for (int off = 1; off < 64; off <<= 1) {
            int u = __shfl_up(v, off);
            if (tid >= off) v += u;
        }
        int ex = v - s;
        exc[2 * tid] = ex;
        exc[2 * tid + 1] = ex + c0;
        if (tid == 63) exc[128] = v;  // == M
    }
    __syncthreads();

    if (tid < nd) {
        row_ptr[d0 + tid] = pos0 + exc[tid];
        dinv[d0 + tid] = rsqrtf((float)(cnt_l[tid] + 1));  // +1 self-loop
    }
    if (b == NBUK - 1 && tid == 0) row_ptr[NN] = pos0 + M;

    if (tid < 128) cur[tid] = exc[tid];
    __syncthreads();

    if (fit) {
        for (int i = tid; i < M; i += 256) {
            unsigned int v = stag[i];
            int r = atomicAdd(&cur[v >> 16], 1);
            stag2[r] = (int)(v & 0xFFFFu);
        }
        __syncthreads();
        for (int i = tid; i < M; i += 256) col[pos0 + i] = stag2[i];
    } else {
        for (int i = tid; i < M; i += 256) {
            unsigned int v = temp[pos0 + i];
            int r = atomicAdd(&cur[v >> 16], 1);
            col[pos0 + r] = (int)(v & 0xFFFFu);
        }
    }
}

// ---------------- GEMM: y[r][h] = bf16( (sum_k x[r][k] * W[k][h]) * dinv[r] ) ----------------
template <int KTOT>
__global__ __launch_bounds__(256) void gemm_tile(const float* __restrict__ x, const float* __restrict__ Wg,
                                                 const float* __restrict__ dinv, unsigned short* __restrict__ y) {
    __shared__ float Xl[64 * 68];
    __shared__ float Wl[64 * 64];
    const int tid = threadIdx.x;
    const int row0 = blockIdx.x * 64;
    const int tc = tid & 15, tr = tid >> 4;
    const int h0 = tc * 4;
    float4 acc[4];
#pragma unroll
    for (int rr = 0; rr < 4; ++rr) acc[rr] = make_float4(0.f, 0.f, 0.f, 0.f);

    for (int kc = 0; kc < KTOT; kc += 64) {
        __syncthreads();
        for (int i = tid; i < 1024; i += 256) {
            int row = i >> 4, c4 = (i & 15) << 2;
            int gr = row0 + row;
            float4 v = make_float4(0.f, 0.f, 0.f, 0.f);
            if (gr < NN) v = *(const float4*)(x + (size_t)gr * KTOT + kc + c4);
            *(float4*)&Xl[row * 68 + c4] = v;
        }
        for (int i = tid; i < 1024; i += 256) {
            int k = i >> 4, h4 = (i & 15) << 2;
            *(float4*)&Wl[k * 64 + h4] = *(const float4*)(Wg + (size_t)(kc + k) * 64 + h4);
        }
        __syncthreads();
#pragma unroll 4
        for (int k = 0; k < 64; k += 4) {
            float4 w0 = *(float4*)&Wl[(k + 0) * 64 + h0];
            float4 w1 = *(float4*)&Wl[(k + 1) * 64 + h0];
            float4 w2 = *(float4*)&Wl[(k + 2) * 64 + h0];
            float4 w3 = *(float4*)&Wl[(k + 3) * 64 + h0];
#pragma unroll
            for (int rr = 0; rr < 4; ++rr) {
                float4 xv = *(float4*)&Xl[(rr * 16 + tr) * 68 + k];
                acc[rr].x += xv.x * w0.x + xv.y * w1.x + xv.z * w2.x + xv.w * w3.x;
                acc[rr].y += xv.x * w0.y + xv.y * w1.y + xv.z * w2.y + xv.w * w3.y;
                acc[rr].z += xv.x * w0.z + xv.y * w1.z + xv.z * w2.z + xv.w * w3.z;
                acc[rr].w += xv.x * w0.w + xv.y * w1.w + xv.z * w2.w + xv.w * w3.w;
            }
        }
    }
#pragma unroll
    for (int rr = 0; rr < 4; ++rr) {
        int r = row0 + rr * 16 + tr;
        if (r < NN) {
            float dv = dinv[r];
            ushort4 o;
            o.x = f2bf(acc[rr].x * dv);
            o.y = f2bf(acc[rr].y * dv);
            o.z = f2bf(acc[rr].z * dv);
            o.w = f2bf(acc[rr].w * dv);
            *(ushort4*)(y + (size_t)r * 64 + h0) = o;
        }
    }
}

// ---------------- Aggregate core (wave = 1 dst; 4 groups x 16 lanes; lane = ushort4 of 4 h) ----------------
// Returns float4 r = dinv*sum + b, reduced across groups (ALL lanes hold result for their l).
__device__ __forceinline__ float4 agg_core(const unsigned short* __restrict__ y, const int* __restrict__ col,
                                           int d, int s0, int s1, int g, int h0,
                                           const float* __restrict__ dinv, const float* __restrict__ b) {
    float4 accA = make_float4(0.f, 0.f, 0.f, 0.f);
    float4 accB = make_float4(0.f, 0.f, 0.f, 0.f);
    if (g == 0) {
        ushort4 sv = *(const ushort4*)(y + (size_t)d * 64 + h0);
        accA.x = bf2f(sv.x); accA.y = bf2f(sv.y); accA.z = bf2f(sv.z); accA.w = bf2f(sv.w);
    }
    int e = s0;
    for (; e + 32 <= s1; e += 32) {
        int a0 = col[e + g], a1 = col[e + 4 + g], a2 = col[e + 8 + g], a3 = col[e + 12 + g];
        int a4 = col[e + 16 + g], a5 = col[e + 20 + g], a6 = col[e + 24 + g], a7 = col[e + 28 + g];
        ushort4 v0 = *(const ushort4*)(y + (size_t)a0 * 64 + h0);
        ushort4 v1 = *(const ushort4*)(y + (size_t)a1 * 64 + h0);
        ushort4 v2 = *(const ushort4*)(y + (size_t)a2 * 64 + h0);
        ushort4 v3 = *(const ushort4*)(y + (size_t)a3 * 64 + h0);
        ushort4 v4 = *(const ushort4*)(y + (size_t)a4 * 64 + h0);
        ushort4 v5 = *(const ushort4*)(y + (size_t)a5 * 64 + h0);
        ushort4 v6 = *(const ushort4*)(y + (size_t)a6 * 64 + h0);
        ushort4 v7 = *(const ushort4*)(y + (size_t)a7 * 64 + h0);
        accA.x += bf2f(v0.x); accA.y += bf2f(v0.y); accA.z += bf2f(v0.z); accA.w += bf2f(v0.w);
        accB.x += bf2f(v1.x); accB.y += bf2f(v1.y); accB.z += bf2f(v1.z); accB.w += bf2f(v1.w);
        accA.x += bf2f(v2.x); accA.y += bf2f(v2.y); accA.z += bf2f(v2.z); accA.w += bf2f(v2.w);
        accB.x += bf2f(v3.x); accB.y += bf2f(v3.y); accB.z += bf2f(v3.z); accB.w += bf2f(v3.w);
        accA.x += bf2f(v4.x); accA.y += bf2f(v4.y); accA.z += bf2f(v4.z); accA.w += bf2f(v4.w);
        accB.x += bf2f(v5.x); accB.y += bf2f(v5.y); accB.z += bf2f(v5.z); accB.w += bf2f(v5.w);
        accA.x += bf2f(v6.x); accA.y += bf2f(v6.y); accA.z += bf2f(v6.z); accA.w += bf2f(v6.w);
        accB.x += bf2f(v7.x); accB.y += bf2f(v7.y); accB.z += bf2f(v7.z); accB.w += bf2f(v7.w);
    }
    for (; e + 8 <= s1; e += 8) {
        int a0 = col[e + g], a1 = col[e + 4 + g];
        ushort4 v0 = *(const ushort4*)(y + (size_t)a0 * 64 + h0);
        ushort4 v1 = *(const ushort4*)(y + (size_t)a1 * 64 + h0);
        accA.x += bf2f(v0.x); accA.y += bf2f(v0.y); accA.z += bf2f(v0.z); accA.w += bf2f(v0.w);
        accB.x += bf2f(v1.x); accB.y += bf2f(v1.y); accB.z += bf2f(v1.z); accB.w += bf2f(v1.w);
    }
    {
        int i0 = e + g, i1 = e + 4 + g;
        if (i0 < s1) {
            int a = col[i0];
            ushort4 v = *(const ushort4*)(y + (size_t)a * 64 + h0);
            accA.x += bf2f(v.x); accA.y += bf2f(v.y); accA.z += bf2f(v.z); accA.w += bf2f(v.w);
        }
        if (i1 < s1) {
            int a = col[i1];
            ushort4 v = *(const ushort4*)(y + (size_t)a * 64 + h0);
            accB.x += bf2f(v.x); accB.y += bf2f(v.y); accB.z += bf2f(v.z); accB.w += bf2f(v.w);
        }
    }
    float4 acc;
    acc.x = accA.x + accB.x; acc.y = accA.y + accB.y;
    acc.z = accA.z + accB.z; acc.w = accA.w + accB.w;
    acc.x += __shfl_xor(acc.x, 16); acc.x += __shfl_xor(acc.x, 32);
    acc.y += __shfl_xor(acc.y, 16); acc.y += __shfl_xor(acc.y, 32);
    acc.z += __shfl_xor(acc.z, 16); acc.z += __shfl_xor(acc.z, 32);
    acc.w += __shfl_xor(acc.w, 16); acc.w += __shfl_xor(acc.w, 32);
    float dv = dinv[d];
    float4 bb = *(const float4*)(b + h0);
    float4 r;
    r.x = dv * acc.x + bb.x;
    r.y = dv * acc.y + bb.y;
    r.z = dv * acc.z + bb.z;
    r.w = dv * acc.w + bb.w;
    return r;
}

__global__ __launch_bounds__(256) void aggregate_kernel(const unsigned short* __restrict__ y,
                                                        const int* __restrict__ row_ptr,
                                                        const int* __restrict__ col, const float* __restrict__ dinv,
                                                        const float* __restrict__ b, float* __restrict__ out, int relu) {
    const int tid = threadIdx.x;
    const int wv = tid >> 6, lane = tid & 63;
    const int g = lane >> 4, l = lane & 15;
    const int h0 = l << 2;
    const int d = blockIdx.x * 4 + wv;
    const int s0 = row_ptr[d], s1 = row_ptr[d + 1];
    float4 r = agg_core(y, col, d, s0, s1, g, h0, dinv, b);
    if (relu) {
        r.x = fmaxf(r.x, 0.f); r.y = fmaxf(r.y, 0.f);
        r.z = fmaxf(r.z, 0.f); r.w = fmaxf(r.w, 0.f);
    }
    if (g == 0) *(float4*)(out + (size_t)d * 64 + h0) = r;
}

// Layer-2 aggregate fused with: relu -> L2 normalize -> write h -> logits -> log_softmax -> write pred.
__global__ __launch_bounds__(256) void aggregate_final_kernel(const unsigned short* __restrict__ y,
                                                              const int* __restrict__ row_ptr,
                                                              const int* __restrict__ col, const float* __restrict__ dinv,
                                                              const float* __restrict__ b,
                                                              const float* __restrict__ W3, const float* __restrict__ b3,
                                                              float* __restrict__ out) {
    const int tid = threadIdx.x;
    const int wv = tid >> 6, lane = tid & 63;
    const int g = lane >> 4, l = lane & 15;
    const int h0 = l << 2;
    const int d = blockIdx.x * 4 + wv;
    const int s0 = row_ptr[d], s1 = row_ptr[d + 1];
    float4 r = agg_core(y, col, d, s0, s1, g, h0, dinv, b);
    r.x = fmaxf(r.x, 0.f); r.y = fmaxf(r.y, 0.f);
    r.z = fmaxf(r.z, 0.f); r.w = fmaxf(r.w, 0.f);

    // L2 norm across 64 h (each l holds 4; groups duplicate) -> reduce over lane bits 0..3
    float sq = r.x * r.x + r.y * r.y + r.z * r.z + r.w * r.w;
    sq += __shfl_xor(sq, 1);
    sq += __shfl_xor(sq, 2);
    sq += __shfl_xor(sq, 4);
    sq += __shfl_xor(sq, 8);
    float inv = 1.0f / fmaxf(sqrtf(sq), 1e-12f);
    float4 hn = make_float4(r.x * inv, r.y * inv, r.z * inv, r.w * inv);

    __shared__ float hl[4][64];
    if (g == 0) {
        *(float4*)(out + 1 + (size_t)NN * C_DIM + (size_t)d * 64 + h0) = hn;
        *(float4*)&hl[wv][h0] = hn;
    }
    __syncthreads();

    // logits + log_softmax (classes in low 4 lane bits)
    int c = lane & 15, chunk = lane >> 4;
    float part = 0.f;
#pragma unroll
    for (int q = 0; q < 16; ++q) {
        int hh = chunk * 16 + q;
        part += hl[wv][hh] * W3[hh * 16 + c];
    }
    part += __shfl_xor(part, 16);
    part += __shfl_xor(part, 32);
    float logit = part + b3[c];

    float m = logit;
#pragma unroll
    for (int off = 8; off > 0; off >>= 1) m = fmaxf(m, __shfl_xor(m, off));
    float ex = __expf(logit - m);
    float se = ex;
#pragma unroll
    for (int off = 8; off > 0; off >>= 1) se += __shfl_xor(se, off);
    float pred = logit - m - __logf(se);
    if (lane < 16) out[1 + (size_t)d * 16 + lane] = pred;
}

__global__ __launch_bounds__(256) void loss_kernel(const float* __restrict__ out, const int* __restrict__ labels,
                                                   const int* __restrict__ train_idx, float* __restrict__ loss_ws) {
    int i = blockIdx.x * 256 + threadIdx.x;
    float v = 0.f;
    if (i < NT) {
        int idx = train_idx[i];
        int lab = labels[idx];
        v = -out[1 + (size_t)idx * 16 + lab];
    }
#pragma unroll
    for (int off = 32; off > 0; off >>= 1) v += __shfl_xor(v, off);
    __shared__ float ws4[4];
    int wv = threadIdx.x >> 6, lane = threadIdx.x & 63;
    if (lane == 0) ws4[wv] = v;
    __syncthreads();
    if (threadIdx.x == 0) atomicAdd(loss_ws, ws4[0] + ws4[1] + ws4[2] + ws4[3]);
}

__global__ void finalize_kernel(const float* __restrict__ loss_ws, float* __restrict__ out) {
    if (threadIdx.x == 0) out[0] = loss_ws[0] * (1.0f / NT);
}

// ---------------- launch ----------------

extern "C" void kernel_launch(void* const* d_in, const int* in_sizes, int n_in,
                              void* d_out, int out_size, void* d_ws, size_t ws_size,
                              hipStream_t stream) {
    const float* feats = (const float*)d_in[0];
    const float* W1 = (const float*)d_in[1];
    const float* b1 = (const float*)d_in[2];
    const float* W2 = (const float*)d_in[3];
    const float* b2 = (const float*)d_in[4];
    const float* W3 = (const float*)d_in[5];
    const float* b3 = (const float*)d_in[6];
    const int* edge_list = (const int*)d_in[7];
    const int* labels = (const int*)d_in[8];
    const int* train_idx = (const int*)d_in[9];
    float* out = (float*)d_out;

    char* w = (char*)d_ws;
    auto alloc = [&](size_t bytes) {
        char* p = w;
        w += (bytes + 255) & ~(size_t)255;
        return p;
    };
    int* row_ptr = (int*)alloc((size_t)(NN + 1) * 4);
    int* col = (int*)alloc((size_t)EE * 4);
    unsigned int* temp = (unsigned int*)alloc((size_t)EE * 4);
    float* dinv = (float*)alloc((size_t)NN * 4);
    unsigned short* yb = (unsigned short*)alloc((size_t)NN * H_DIM * 2);
    float* bufB = (float*)alloc((size_t)NN * H_DIM * 4);
    float* loss_ws = (float*)alloc(4);
    int* bhist = (int*)alloc((size_t)NBUK * 4);
    int* bucket_base = (int*)alloc((size_t)(NBUK + 1) * 4);
    int* bucket_cursor = (int*)alloc((size_t)NBUK * 4);

    const int* srcp = edge_list;
    const int* dstp = edge_list + EE;

    zero_kernel<<<2, 256, 0, stream>>>(bhist, loss_ws);
    bucket_hist_kernel<<<NCHUNK, 256, 0, stream>>>(dstp, bhist);
    bucket_scan_kernel<<<1, 64, 0, stream>>>(bhist, bucket_base, bucket_cursor);
    multisplit_kernel<<<NCHUNK, 256, 0, stream>>>(srcp, dstp, bucket_cursor, temp);
    bucket_finalize_kernel<<<NBUK, 256, 0, stream>>>(temp, bucket_base, row_ptr, dinv, col);

    const int GB = (NN + 63) / 64;  // 782
    // layer 0: feats @ W1, no relu
    gemm_tile<256><<<GB, 256, 0, stream>>>(feats, W1, dinv, yb);
    aggregate_kernel<<<NN / 4, 256, 0, stream>>>(yb, row_ptr, col, dinv, b1, bufB, 0);
    // layer 1: relu
    gemm_tile<64><<<GB, 256, 0, stream>>>(bufB, W2, dinv, yb);
    aggregate_kernel<<<NN / 4, 256, 0, stream>>>(yb, row_ptr, col, dinv, b2, bufB, 1);
    // layer 2: gemm, then fused aggregate+relu+normalize+logits+log_softmax
    gemm_tile<64><<<GB, 256, 0, stream>>>(bufB, W2 + H_DIM * H_DIM, dinv, yb);
    aggregate_final_kernel<<<NN / 4, 256, 0, stream>>>(yb, row_ptr, col, dinv, b2 + H_DIM, W3, b3, out);

    loss_kernel<<<(NT + 255) / 256, 256, 0, stream>>>(out, labels, train_idx, loss_ws);
    finalize_kernel<<<1, 64, 0, stream>>>(loss_ws, out);
}

// Round 8
// 311.591 us; speedup vs baseline: 2.3132x; 1.0385x over previous
//
#include <hip/hip_runtime.h>
#include <math.h>

#define NN 50000
#define EE 1600000
#define IN_DIM 256
#define H_DIM 64
#define C_DIM 16
#define NT 5000
#define NBUK 391  // ceil(NN/128)
#define CHUNK 8192
#define NCHUNK 196  // ceil(EE/CHUNK)
#define CAP 6144

typedef short bf16x8 __attribute__((ext_vector_type(8)));
typedef float f32x4 __attribute__((ext_vector_type(4)));

__device__ __forceinline__ unsigned short f2bf(float f) {
    unsigned int u = __float_as_uint(f);
    u = (u + 0x7FFFu + ((u >> 16) & 1u)) >> 16;  // round-to-nearest-even
    return (unsigned short)u;
}
__device__ __forceinline__ float bf2f(unsigned short s) {
    return __uint_as_float(((unsigned int)s) << 16);
}

// ---------------- CSR build ----------------

__global__ __launch_bounds__(256) void zero_kernel(int* __restrict__ bhist, float* __restrict__ loss_ws) {
    int i = blockIdx.x * 256 + threadIdx.x;
    if (i < NBUK) bhist[i] = 0;
    if (i == 0) *(int*)loss_ws = 0;
}

__global__ __launch_bounds__(256) void bucket_hist_kernel(const int* __restrict__ dst, int* __restrict__ bhist) {
    __shared__ int hist[NBUK];
    const int tid = threadIdx.x;
    const int base_e = blockIdx.x * CHUNK;
    for (int i = tid; i < NBUK; i += 256) hist[i] = 0;
    __syncthreads();
    for (int i = tid; i < CHUNK; i += 256) {
        int e = base_e + i;
        if (e < EE) atomicAdd(&hist[dst[e] >> 7], 1);
    }
    __syncthreads();
    for (int i = tid; i < NBUK; i += 256) {
        int c = hist[i];
        if (c) atomicAdd(&bhist[i], c);
    }
}

__global__ __launch_bounds__(64) void bucket_scan_kernel(const int* __restrict__ bhist, int* __restrict__ bucket_base,
                                                         int* __restrict__ bucket_cursor) {
    int lane = threadIdx.x;
    int lc[7];
    int s = 0;
#pragma unroll
    for (int k = 0; k < 7; ++k) {
        int idx = lane * 7 + k;
        int c = (idx < NBUK) ? bhist[idx] : 0;
        lc[k] = c;
        s += c;
    }
    int v = s;
#pragma unroll
    for (int off = 1; off < 64; off <<= 1) {
        int u = __shfl_up(v, off);
        if (lane >= off) v += u;
    }
    int ex = v - s;
#pragma unroll
    for (int k = 0; k < 7; ++k) {
        int idx = lane * 7 + k;
        if (idx < NBUK) { bucket_base[idx] = ex; bucket_cursor[idx] = ex; }
        ex += lc[k];
    }
    if (lane == 63) bucket_base[NBUK] = v;  // == EE
}

__global__ __launch_bounds__(256) void multisplit_kernel(const int* __restrict__ src, const int* __restrict__ dst,
                                                         int* __restrict__ bucket_cursor,
                                                         unsigned int* __restrict__ temp) {
    __shared__ int hist[NBUK];
    __shared__ int excl[NBUK + 1];
    __shared__ int offs[NBUK];
    __shared__ int delta[NBUK];
    __shared__ unsigned short bid[CHUNK];
    __shared__ unsigned int stag[CHUNK];

    const int tid = threadIdx.x;
    const int base_e = blockIdx.x * CHUNK;

    for (int i = tid; i < NBUK; i += 256) hist[i] = 0;
    __syncthreads();

    for (int i = tid; i < CHUNK; i += 256) {
        int e = base_e + i;
        if (e < EE) atomicAdd(&hist[dst[e] >> 7], 1);
    }
    __syncthreads();

    if (tid < 64) {
        int lane = tid;
        int lc[7];
        int s = 0;
#pragma unroll
        for (int k = 0; k < 7; ++k) {
            int idx = lane * 7 + k;
            int c = (idx < NBUK) ? hist[idx] : 0;
            lc[k] = c;
            s += c;
        }
        int v = s;
#pragma unroll
        for (int off = 1; off < 64; off <<= 1) {
            int u = __shfl_up(v, off);
            if (lane >= off) v += u;
        }
        int ex = v - s;
#pragma unroll
        for (int k = 0; k < 7; ++k) {
            int idx = lane * 7 + k;
            if (idx < NBUK) excl[idx] = ex;
            ex += lc[k];
        }
        if (lane == 63) excl[NBUK] = v;
    }
    __syncthreads();

    for (int b = tid; b < NBUK; b += 256) {
        int count = excl[b + 1] - excl[b];
        int gbase = atomicAdd(&bucket_cursor[b], count);
        delta[b] = gbase - excl[b];
        offs[b] = excl[b];
    }
    __syncthreads();

    for (int i = tid; i < CHUNK; i += 256) {
        int e = base_e + i;
        if (e < EE) {
            int d = dst[e];
            int s = src[e];
            int b = d >> 7;
            int rank = atomicAdd(&offs[b], 1);
            stag[rank] = (unsigned int)(((d & 127) << 16) | s);
            bid[rank] = (unsigned short)b;
        }
    }
    __syncthreads();

    int nval = excl[NBUK];
    for (int i = tid; i < nval; i += 256) {
        int b = bid[i];
        temp[delta[b] + i] = stag[i];
    }
}

__global__ __launch_bounds__(256) void bucket_finalize_kernel(const unsigned int* __restrict__ temp,
                                                              const int* __restrict__ bucket_base,
                                                              int* __restrict__ row_ptr, float* __restrict__ dinv,
                                                              int* __restrict__ col) {
    __shared__ int cnt_l[128];
    __shared__ int exc[129];
    __shared__ int cur[128];
    __shared__ unsigned int stag[CAP];
    __shared__ int stag2[CAP];
    const int b = blockIdx.x;
    const int tid = threadIdx.x;
    const int d0 = b << 7;
    const int nd = (d0 + 128 < NN) ? 128 : (NN - d0);
    const int pos0 = bucket_base[b];
    const int M = bucket_base[b + 1] - pos0;
    const bool fit = (M <= CAP);

    for (int j = tid; j < 128; j += 256) cnt_l[j] = 0;
    __syncthreads();

    for (int i = tid; i < M; i += 256) {
        unsigned int v = temp[pos0 + i];
        if (fit) stag[i] = v;
        atomicAdd(&cnt_l[v >> 16], 1);
    }
    __syncthreads();

    if (tid < 64) {
        int c0 = cnt_l[2 * tid], c1 = cnt_l[2 * tid + 1];
        int s = c0 + c1;
        int v = s;
#pragma unroll
        for (int off = 1; off < 64; off <<= 1) {
            int u = __shfl_up(v, off);
            if (tid >= off) v += u;
        }
        int ex = v - s;
        exc[2 * tid] = ex;
        exc[2 * tid + 1] = ex + c0;
        if (tid == 63) exc[128] = v;  // == M
    }
    __syncthreads();

    if (tid < nd) {
        row_ptr[d0 + tid] = pos0 + exc[tid];
        dinv[d0 + tid] = rsqrtf((float)(cnt_l[tid] + 1));  // +1 self-loop
    }
    if (b == NBUK - 1 && tid == 0) row_ptr[NN] = pos0 + M;

    if (tid < 128) cur[tid] = exc[tid];
    __syncthreads();

    if (fit) {
        for (int i = tid; i < M; i += 256) {
            unsigned int v = stag[i];
            int r = atomicAdd(&cur[v >> 16], 1);
            stag2[r] = (int)(v & 0xFFFFu);
        }
        __syncthreads();
        for (int i = tid; i < M; i += 256) col[pos0 + i] = stag2[i];
    } else {
        for (int i = tid; i < M; i += 256) {
            unsigned int v = temp[pos0 + i];
            int r = atomicAdd(&cur[v >> 16], 1);
            col[pos0 + r] = (int)(v & 0xFFFFu);
        }
    }
}

// ---------------- MFMA GEMM: y[r][h] = bf16( (x@W)[r][h] * dinv[r] ) ----------------
// 64x64 tile, 4 waves, wave = 16-row strip x 4 col-tiles, mfma_f32_16x16x32_bf16.
// fp32 inputs converted to bf16 at LDS stage time; fp32 accumulate.
template <int KTOT>
__global__ __launch_bounds__(256) void gemm_mfma(const float* __restrict__ x, const float* __restrict__ Wg,
                                                 const float* __restrict__ dinv, unsigned short* __restrict__ y) {
    __shared__ unsigned short As[64 * 72];  // [row][k], stride 72
    __shared__ unsigned short Bs[64 * 72];  // [n][k] (W transposed), stride 72
    const int tid = threadIdx.x;
    const int wv = tid >> 6, lane = tid & 63;
    const int mn = lane & 15, quad = lane >> 4;
    const int row0 = blockIdx.x * 64;

    f32x4 acc[4];
#pragma unroll
    for (int t = 0; t < 4; ++t) acc[t] = (f32x4){0.f, 0.f, 0.f, 0.f};

    for (int k0 = 0; k0 < KTOT; k0 += 64) {
        __syncthreads();
        // stage A: 64 rows x 64 k, fp32 -> bf16 (coalesced float4 reads)
#pragma unroll
        for (int it = 0; it < 4; ++it) {
            int i = tid + 256 * it;
            int row = i >> 4, c4 = (i & 15) << 2;
            int gr = row0 + row;
            float4 v = make_float4(0.f, 0.f, 0.f, 0.f);
            if (gr < NN) v = *(const float4*)(x + (size_t)gr * KTOT + k0 + c4);
            ushort4 o;
            o.x = f2bf(v.x); o.y = f2bf(v.y); o.z = f2bf(v.z); o.w = f2bf(v.w);
            *(ushort4*)&As[row * 72 + c4] = o;
        }
        // stage B transposed: W[k][n] -> Bs[n][k]
#pragma unroll
        for (int it = 0; it < 16; ++it) {
            int i = tid + 256 * it;
            int k = i >> 6, n = i & 63;
            Bs[n * 72 + k] = f2bf(Wg[(size_t)(k0 + k) * 64 + n]);
        }
        __syncthreads();
#pragma unroll
        for (int kk = 0; kk < 2; ++kk) {
            bf16x8 a = *(const bf16x8*)&As[(wv * 16 + mn) * 72 + kk * 32 + quad * 8];
#pragma unroll
            for (int t = 0; t < 4; ++t) {
                bf16x8 bfr = *(const bf16x8*)&Bs[(t * 16 + mn) * 72 + kk * 32 + quad * 8];
                acc[t] = __builtin_amdgcn_mfma_f32_16x16x32_bf16(a, bfr, acc[t], 0, 0, 0);
            }
        }
    }
    __syncthreads();
    // epilogue: scale by dinv, bf16, stage into As (reuse) as [row][col] stride 72
    float dv[4];
#pragma unroll
    for (int r = 0; r < 4; ++r) {
        int gr = row0 + wv * 16 + quad * 4 + r;
        dv[r] = (gr < NN) ? dinv[gr] : 0.f;
    }
#pragma unroll
    for (int t = 0; t < 4; ++t) {
#pragma unroll
        for (int r = 0; r < 4; ++r) {
            int row_l = wv * 16 + quad * 4 + r;
            int col = t * 16 + mn;
            As[row_l * 72 + col] = f2bf(acc[t][r] * dv[r]);
        }
    }
    __syncthreads();
    // coalesced bf16 store: 64 rows x 64 cols
#pragma unroll
    for (int it = 0; it < 2; ++it) {
        int i = tid + 256 * it;
        int row = i >> 3, c8 = (i & 7) << 3;
        int gr = row0 + row;
        if (gr < NN) {
            uint4 v = *(uint4*)&As[row * 72 + c8];
            *(uint4*)(y + (size_t)gr * 64 + c8) = v;
        }
    }
}

// ---------------- Aggregate core (wave = 1 dst; 4 groups x 16 lanes; lane = ushort4 of 4 h) ----------------
__device__ __forceinline__ float4 agg_core(const unsigned short* __restrict__ y, const int* __restrict__ col,
                                           int d, int s0, int s1, int g, int h0,
                                           const float* __restrict__ dinv, const float* __restrict__ b) {
    float4 accA = make_float4(0.f, 0.f, 0.f, 0.f);
    float4 accB = make_float4(0.f, 0.f, 0.f, 0.f);
    if (g == 0) {
        ushort4 sv = *(const ushort4*)(y + (size_t)d * 64 + h0);
        accA.x = bf2f(sv.x); accA.y = bf2f(sv.y); accA.z = bf2f(sv.z); accA.w = bf2f(sv.w);
    }
    int e = s0;
    for (; e + 32 <= s1; e += 32) {
        int a0 = col[e + g], a1 = col[e + 4 + g], a2 = col[e + 8 + g], a3 = col[e + 12 + g];
        int a4 = col[e + 16 + g], a5 = col[e + 20 + g], a6 = col[e + 24 + g], a7 = col[e + 28 + g];
        ushort4 v0 = *(const ushort4*)(y + (size_t)a0 * 64 + h0);
        ushort4 v1 = *(const ushort4*)(y + (size_t)a1 * 64 + h0);
        ushort4 v2 = *(const ushort4*)(y + (size_t)a2 * 64 + h0);
        ushort4 v3 = *(const ushort4*)(y + (size_t)a3 * 64 + h0);
        ushort4 v4 = *(const ushort4*)(y + (size_t)a4 * 64 + h0);
        ushort4 v5 = *(const ushort4*)(y + (size_t)a5 * 64 + h0);
        ushort4 v6 = *(const ushort4*)(y + (size_t)a6 * 64 + h0);
        ushort4 v7 = *(const ushort4*)(y + (size_t)a7 * 64 + h0);
        accA.x += bf2f(v0.x); accA.y += bf2f(v0.y); accA.z += bf2f(v0.z); accA.w += bf2f(v0.w);
        accB.x += bf2f(v1.x); accB.y += bf2f(v1.y); accB.z += bf2f(v1.z); accB.w += bf2f(v1.w);
        accA.x += bf2f(v2.x); accA.y += bf2f(v2.y); accA.z += bf2f(v2.z); accA.w += bf2f(v2.w);
        accB.x += bf2f(v3.x); accB.y += bf2f(v3.y); accB.z += bf2f(v3.z); accB.w += bf2f(v3.w);
        accA.x += bf2f(v4.x); accA.y += bf2f(v4.y); accA.z += bf2f(v4.z); accA.w += bf2f(v4.w);
        accB.x += bf2f(v5.x); accB.y += bf2f(v5.y); accB.z += bf2f(v5.z); accB.w += bf2f(v5.w);
        accA.x += bf2f(v6.x); accA.y += bf2f(v6.y); accA.z += bf2f(v6.z); accA.w += bf2f(v6.w);
        accB.x += bf2f(v7.x); accB.y += bf2f(v7.y); accB.z += bf2f(v7.z); accB.w += bf2f(v7.w);
    }
    for (; e + 8 <= s1; e += 8) {
        int a0 = col[e + g], a1 = col[e + 4 + g];
        ushort4 v0 = *(const ushort4*)(y + (size_t)a0 * 64 + h0);
        ushort4 v1 = *(const ushort4*)(y + (size_t)a1 * 64 + h0);
        accA.x += bf2f(v0.x); accA.y += bf2f(v0.y); accA.z += bf2f(v0.z); accA.w += bf2f(v0.w);
        accB.x += bf2f(v1.x); accB.y += bf2f(v1.y); accB.z += bf2f(v1.z); accB.w += bf2f(v1.w);
    }
    {
        int i0 = e + g, i1 = e + 4 + g;
        if (i0 < s1) {
            int a = col[i0];
            ushort4 v = *(const ushort4*)(y + (size_t)a * 64 + h0);
            accA.x += bf2f(v.x); accA.y += bf2f(v.y); accA.z += bf2f(v.z); accA.w += bf2f(v.w);
        }
        if (i1 < s1) {
            int a = col[i1];
            ushort4 v = *(const ushort4*)(y + (size_t)a * 64 + h0);
            accB.x += bf2f(v.x); accB.y += bf2f(v.y); accB.z += bf2f(v.z); accB.w += bf2f(v.w);
        }
    }
    float4 acc;
    acc.x = accA.x + accB.x; acc.y = accA.y + accB.y;
    acc.z = accA.z + accB.z; acc.w = accA.w + accB.w;
    acc.x += __shfl_xor(acc.x, 16); acc.x += __shfl_xor(acc.x, 32);
    acc.y += __shfl_xor(acc.y, 16); acc.y += __shfl_xor(acc.y, 32);
    acc.z += __shfl_xor(acc.z, 16); acc.z += __shfl_xor(acc.z, 32);
    acc.w += __shfl_xor(acc.w, 16); acc.w += __shfl_xor(acc.w, 32);
    float dv = dinv[d];
    float4 bb = *(const float4*)(b + h0);
    float4 r;
    r.x = dv * acc.x + bb.x;
    r.y = dv * acc.y + bb.y;
    r.z = dv * acc.z + bb.z;
    r.w = dv * acc.w + bb.w;
    return r;
}

__global__ __launch_bounds__(256) void aggregate_kernel(const unsigned short* __restrict__ y,
                                                        const int* __restrict__ row_ptr,
                                                        const int* __restrict__ col, const float* __restrict__ dinv,
                                                        const float* __restrict__ b, float* __restrict__ out, int relu) {
    const int tid = threadIdx.x;
    const int wv = tid >> 6, lane = tid & 63;
    const int g = lane >> 4, l = lane & 15;
    const int h0 = l << 2;
    const int d = blockIdx.x * 4 + wv;
    const int s0 = row_ptr[d], s1 = row_ptr[d + 1];
    float4 r = agg_core(y, col, d, s0, s1, g, h0, dinv, b);
    if (relu) {
        r.x = fmaxf(r.x, 0.f); r.y = fmaxf(r.y, 0.f);
        r.z = fmaxf(r.z, 0.f); r.w = fmaxf(r.w, 0.f);
    }
    if (g == 0) *(float4*)(out + (size_t)d * 64 + h0) = r;
}

// Layer-2 aggregate fused with: relu -> L2 normalize -> write h -> logits -> log_softmax -> write pred.
__global__ __launch_bounds__(256) void aggregate_final_kernel(const unsigned short* __restrict__ y,
                                                              const int* __restrict__ row_ptr,
                                                              const int* __restrict__ col, const float* __restrict__ dinv,
                                                              const float* __restrict__ b,
                                                              const float* __restrict__ W3, const float* __restrict__ b3,
                                                              float* __restrict__ out) {
    const int tid = threadIdx.x;
    const int wv = tid >> 6, lane = tid & 63;
    const int g = lane >> 4, l = lane & 15;
    const int h0 = l << 2;
    const int d = blockIdx.x * 4 + wv;
    const int s0 = row_ptr[d], s1 = row_ptr[d + 1];
    float4 r = agg_core(y, col, d, s0, s1, g, h0, dinv, b);
    r.x = fmaxf(r.x, 0.f); r.y = fmaxf(r.y, 0.f);
    r.z = fmaxf(r.z, 0.f); r.w = fmaxf(r.w, 0.f);

    float sq = r.x * r.x + r.y * r.y + r.z * r.z + r.w * r.w;
    sq += __shfl_xor(sq, 1);
    sq += __shfl_xor(sq, 2);
    sq += __shfl_xor(sq, 4);
    sq += __shfl_xor(sq, 8);
    float inv = 1.0f / fmaxf(sqrtf(sq), 1e-12f);
    float4 hn = make_float4(r.x * inv, r.y * inv, r.z * inv, r.w * inv);

    __shared__ float hl[4][64];
    if (g == 0) {
        *(float4*)(out + 1 + (size_t)NN * C_DIM + (size_t)d * 64 + h0) = hn;
        *(float4*)&hl[wv][h0] = hn;
    }
    __syncthreads();

    int c = lane & 15, chunk = lane >> 4;
    float part = 0.f;
#pragma unroll
    for (int q = 0; q < 16; ++q) {
        int hh = chunk * 16 + q;
        part += hl[wv][hh] * W3[hh * 16 + c];
    }
    part += __shfl_xor(part, 16);
    part += __shfl_xor(part, 32);
    float logit = part + b3[c];

    float m = logit;
#pragma unroll
    for (int off = 8; off > 0; off >>= 1) m = fmaxf(m, __shfl_xor(m, off));
    float ex = __expf(logit - m);
    float se = ex;
#pragma unroll
    for (int off = 8; off > 0; off >>= 1) se += __shfl_xor(se, off);
    float pred = logit - m - __logf(se);
    if (lane < 16) out[1 + (size_t)d * 16 + lane] = pred;
}

__global__ __launch_bounds__(256) void loss_kernel(const float* __restrict__ out, const int* __restrict__ labels,
                                                   const int* __restrict__ train_idx, float* __restrict__ loss_ws) {
    int i = blockIdx.x * 256 + threadIdx.x;
    float v = 0.f;
    if (i < NT) {
        int idx = train_idx[i];
        int lab = labels[idx];
        v = -out[1 + (size_t)idx * 16 + lab];
    }
#pragma unroll
    for (int off = 32; off > 0; off >>= 1) v += __shfl_xor(v, off);
    __shared__ float ws4[4];
    int wv = threadIdx.x >> 6, lane = threadIdx.x & 63;
    if (lane == 0) ws4[wv] = v;
    __syncthreads();
    if (threadIdx.x == 0) atomicAdd(loss_ws, ws4[0] + ws4[1] + ws4[2] + ws4[3]);
}

__global__ void finalize_kernel(const float* __restrict__ loss_ws, float* __restrict__ out) {
    if (threadIdx.x == 0) out[0] = loss_ws[0] * (1.0f / NT);
}

// ---------------- launch ----------------

extern "C" void kernel_launch(void* const* d_in, const int* in_sizes, int n_in,
                              void* d_out, int out_size, void* d_ws, size_t ws_size,
                              hipStream_t stream) {
    const float* feats = (const float*)d_in[0];
    const float* W1 = (const float*)d_in[1];
    const float* b1 = (const float*)d_in[2];
    const float* W2 = (const float*)d_in[3];
    const float* b2 = (const float*)d_in[4];
    const float* W3 = (const float*)d_in[5];
    const float* b3 = (const float*)d_in[6];
    const int* edge_list = (const int*)d_in[7];
    const int* labels = (const int*)d_in[8];
    const int* train_idx = (const int*)d_in[9];
    float* out = (float*)d_out;

    char* w = (char*)d_ws;
    auto alloc = [&](size_t bytes) {
        char* p = w;
        w += (bytes + 255) & ~(size_t)255;
        return p;
    };
    int* row_ptr = (int*)alloc((size_t)(NN + 1) * 4);
    int* col = (int*)alloc((size_t)EE * 4);
    unsigned int* temp = (unsigned int*)alloc((size_t)EE * 4);
    float* dinv = (float*)alloc((size_t)NN * 4);
    unsigned short* yb = (unsigned short*)alloc((size_t)NN * H_DIM * 2);
    float* bufB = (float*)alloc((size_t)NN * H_DIM * 4);
    float* loss_ws = (float*)alloc(4);
    int* bhist = (int*)alloc((size_t)NBUK * 4);
    int* bucket_base = (int*)alloc((size_t)(NBUK + 1) * 4);
    int* bucket_cursor = (int*)alloc((size_t)NBUK * 4);

    const int* srcp = edge_list;
    const int* dstp = edge_list + EE;

    zero_kernel<<<2, 256, 0, stream>>>(bhist, loss_ws);
    bucket_hist_kernel<<<NCHUNK, 256, 0, stream>>>(dstp, bhist);
    bucket_scan_kernel<<<1, 64, 0, stream>>>(bhist, bucket_base, bucket_cursor);
    multisplit_kernel<<<NCHUNK, 256, 0, stream>>>(srcp, dstp, bucket_cursor, temp);
    bucket_finalize_kernel<<<NBUK, 256, 0, stream>>>(temp, bucket_base, row_ptr, dinv, col);

    const int GB = (NN + 63) / 64;  // 782
    // layer 0: feats @ W1, no relu
    gemm_mfma<256><<<GB, 256, 0, stream>>>(feats, W1, dinv, yb);
    aggregate_kernel<<<NN / 4, 256, 0, stream>>>(yb, row_ptr, col, dinv, b1, bufB, 0);
    // layer 1: relu
    gemm_mfma<64><<<GB, 256, 0, stream>>>(bufB, W2, dinv, yb);
    aggregate_kernel<<<NN / 4, 256, 0, stream>>>(yb, row_ptr, col, dinv, b2, bufB, 1);
    // layer 2: gemm, then fused aggregate+relu+normalize+logits+log_softmax
    gemm_mfma<64><<<GB, 256, 0, stream>>>(bufB, W2 + H_DIM * H_DIM, dinv, yb);
    aggregate_final_kernel<<<NN / 4, 256, 0, stream>>>(yb, row_ptr, col, dinv, b2 + H_DIM, W3, b3, out);

    loss_kernel<<<(NT + 255) / 256, 256, 0, stream>>>(out, labels, train_idx, loss_ws);
    finalize_kernel<<<1, 64, 0, stream>>>(loss_ws, out);
}

// Round 9
// 291.701 us; speedup vs baseline: 2.4709x; 1.0682x over previous
//
#include <hip/hip_runtime.h>
#include <math.h>

#define NN 50000
#define EE 1600000
#define IN_DIM 256
#define H_DIM 64
#define C_DIM 16
#define NT 5000
#define NBUK 391  // ceil(NN/128)
#define CHUNK 8192
#define NCHUNK 196  // ceil(EE/CHUNK)
#define PAD 6144   // per-bucket capacity (expected load 4092, sigma ~64)
#define CAP 6144

typedef short bf16x8 __attribute__((ext_vector_type(8)));
typedef float f32x4 __attribute__((ext_vector_type(4)));

__device__ __forceinline__ unsigned short f2bf(float f) {
    unsigned int u = __float_as_uint(f);
    u = (u + 0x7FFFu + ((u >> 16) & 1u)) >> 16;  // RNE
    return (unsigned short)u;
}
__device__ __forceinline__ void acc_dw(float2& a, unsigned u) {
    a.x += __uint_as_float(u << 16);
    a.y += __uint_as_float(u & 0xFFFF0000u);
}
__device__ __forceinline__ void acc_u4(float2* acc, uint4 v) {
    acc_dw(acc[0], v.x); acc_dw(acc[1], v.y); acc_dw(acc[2], v.z); acc_dw(acc[3], v.w);
}

// ---------------- init: per-bucket cursors at padded bases ----------------
__global__ __launch_bounds__(256) void zero_kernel(int* __restrict__ cursor, float* __restrict__ loss_ws) {
    int i = blockIdx.x * 256 + threadIdx.x;
    if (i < NBUK) cursor[i] = i * PAD;
    if (i == 0) loss_ws[0] = 0.f;
}

// ---------------- pre-convert weights to bf16, transposed [n][k] ----------------
__global__ __launch_bounds__(256) void prep_weights(const float* __restrict__ W1, const float* __restrict__ W2,
                                                    unsigned short* __restrict__ WT1, unsigned short* __restrict__ WT2) {
    int i = blockIdx.x * 256 + threadIdx.x;
    if (i < 64 * 256) {
        int n = i >> 8, k = i & 255;
        WT1[i] = f2bf(W1[k * 64 + n]);
    }
    int j = i - 64 * 256;
    if (j >= 0 && j < 2 * 64 * 64) {
        int l = j >> 12, r = j & 4095;
        int n = r >> 6, k = r & 63;
        WT2[j] = f2bf(W2[l * 4096 + k * 64 + n]);
    }
}

// ---------------- multisplit into padded per-bucket regions ----------------
__global__ __launch_bounds__(256) void multisplit_kernel(const int* __restrict__ src, const int* __restrict__ dst,
                                                         int* __restrict__ cursor, unsigned int* __restrict__ temp) {
    __shared__ int hist[NBUK];
    __shared__ int excl[NBUK + 1];
    __shared__ int offs[NBUK];
    __shared__ int delta[NBUK];
    __shared__ unsigned short bid[CHUNK];
    __shared__ unsigned int stag[CHUNK];

    const int tid = threadIdx.x;
    const int base_e = blockIdx.x * CHUNK;

    for (int i = tid; i < NBUK; i += 256) hist[i] = 0;
    __syncthreads();

    for (int i = tid; i < CHUNK; i += 256) {
        int e = base_e + i;
        if (e < EE) atomicAdd(&hist[dst[e] >> 7], 1);
    }
    __syncthreads();

    if (tid < 64) {
        int lane = tid;
        int lc[7];
        int s = 0;
#pragma unroll
        for (int k = 0; k < 7; ++k) {
            int idx = lane * 7 + k;
            int c = (idx < NBUK) ? hist[idx] : 0;
            lc[k] = c;
            s += c;
        }
        int v = s;
#pragma unroll
        for (int off = 1; off < 64; off <<= 1) {
            int u = __shfl_up(v, off);
            if (lane >= off) v += u;
        }
        int ex = v - s;
#pragma unroll
        for (int k = 0; k < 7; ++k) {
            int idx = lane * 7 + k;
            if (idx < NBUK) excl[idx] = ex;
            ex += lc[k];
        }
        if (lane == 63) excl[NBUK] = v;
    }
    __syncthreads();

    for (int b = tid; b < NBUK; b += 256) {
        int count = excl[b + 1] - excl[b];
        int gbase = atomicAdd(&cursor[b], count);
        delta[b] = gbase - excl[b];
        offs[b] = excl[b];
    }
    __syncthreads();

    for (int i = tid; i < CHUNK; i += 256) {
        int e = base_e + i;
        if (e < EE) {
            int d = dst[e];
            int s = src[e];
            int b = d >> 7;
            int rank = atomicAdd(&offs[b], 1);
            stag[rank] = (unsigned int)(((d & 127) << 16) | s);
            bid[rank] = (unsigned short)b;
        }
    }
    __syncthreads();

    int nval = excl[NBUK];
    for (int i = tid; i < nval; i += 256) {
        int b = bid[i];
        temp[delta[b] + i] = stag[i];
    }
}

// ---------------- per-bucket finalize: counts -> row_beg/row_end + dinv, place col ----------------
__global__ __launch_bounds__(256) void bucket_finalize_kernel(const unsigned int* __restrict__ temp,
                                                              const int* __restrict__ cursor,
                                                              int* __restrict__ row_beg, int* __restrict__ row_end,
                                                              float* __restrict__ dinv, int* __restrict__ col) {
    __shared__ int cnt_l[128];
    __shared__ int exc[129];
    __shared__ int cur[128];
    __shared__ unsigned int stag[CAP];
    __shared__ int stag2[CAP];
    const int b = blockIdx.x;
    const int tid = threadIdx.x;
    const int d0 = b << 7;
    const int nd = (d0 + 128 < NN) ? 128 : (NN - d0);
    const int base = b * PAD;
    int M = cursor[b] - base;
    if (M > CAP) M = CAP;  // statistically unreachable

    for (int j = tid; j < 128; j += 256) cnt_l[j] = 0;
    __syncthreads();

    for (int i = tid; i < M; i += 256) {
        unsigned int v = temp[base + i];
        stag[i] = v;
        atomicAdd(&cnt_l[v >> 16], 1);
    }
    __syncthreads();

    if (tid < 64) {
        int c0 = cnt_l[2 * tid], c1 = cnt_l[2 * tid + 1];
        int s = c0 + c1;
        int v = s;
#pragma unroll
        for (int off = 1; off < 64; off <<= 1) {
            int u = __shfl_up(v, off);
            if (tid >= off) v += u;
        }
        int ex = v - s;
        exc[2 * tid] = ex;
        exc[2 * tid + 1] = ex + c0;
        if (tid == 63) exc[128] = v;  // == M
    }
    __syncthreads();

    if (tid < nd) {
        row_beg[d0 + tid] = base + exc[tid];
        row_end[d0 + tid] = base + exc[tid + 1];
        dinv[d0 + tid] = rsqrtf((float)(cnt_l[tid] + 1));  // +1 self-loop
    }

    if (tid < 128) cur[tid] = exc[tid];
    __syncthreads();

    for (int i = tid; i < M; i += 256) {
        unsigned int v = stag[i];
        int r = atomicAdd(&cur[v >> 16], 1);
        stag2[r] = (int)(v & 0xFFFFu);
    }
    __syncthreads();
    for (int i = tid; i < M; i += 256) col[base + i] = stag2[i];
}

// ---------------- GEMM layer 0: fp32 feats (LDS-staged, cvt) x WT1 (direct global B frags) ----------------
__global__ __launch_bounds__(256) void gemm0_mfma(const float* __restrict__ x, const unsigned short* __restrict__ WT,
                                                  const float* __restrict__ dinv, unsigned short* __restrict__ y) {
    __shared__ unsigned short As[64 * 72];
    const int tid = threadIdx.x;
    const int wv = tid >> 6, lane = tid & 63;
    const int mn = lane & 15, quad = lane >> 4;
    const int row0 = blockIdx.x * 64;

    f32x4 acc[4];
#pragma unroll
    for (int t = 0; t < 4; ++t) acc[t] = (f32x4){0.f, 0.f, 0.f, 0.f};

    for (int k0 = 0; k0 < 256; k0 += 64) {
        __syncthreads();
#pragma unroll
        for (int it = 0; it < 4; ++it) {
            int i = tid + 256 * it;
            int row = i >> 4, c4 = (i & 15) << 2;
            int gr = row0 + row;
            float4 v = make_float4(0.f, 0.f, 0.f, 0.f);
            if (gr < NN) v = *(const float4*)(x + (size_t)gr * 256 + k0 + c4);
            ushort4 o;
            o.x = f2bf(v.x); o.y = f2bf(v.y); o.z = f2bf(v.z); o.w = f2bf(v.w);
            *(ushort4*)&As[row * 72 + c4] = o;
        }
        __syncthreads();
#pragma unroll
        for (int kk = 0; kk < 2; ++kk) {
            bf16x8 a = *(const bf16x8*)&As[(wv * 16 + mn) * 72 + kk * 32 + quad * 8];
#pragma unroll
            for (int t = 0; t < 4; ++t) {
                bf16x8 bfr = *(const bf16x8*)(WT + (t * 16 + mn) * 256 + k0 + kk * 32 + quad * 8);
                acc[t] = __builtin_amdgcn_mfma_f32_16x16x32_bf16(a, bfr, acc[t], 0, 0, 0);
            }
        }
    }
    __syncthreads();
    float dv[4];
#pragma unroll
    for (int r = 0; r < 4; ++r) {
        int gr = row0 + wv * 16 + quad * 4 + r;
        dv[r] = (gr < NN) ? dinv[gr] : 0.f;
    }
#pragma unroll
    for (int t = 0; t < 4; ++t)
#pragma unroll
        for (int r = 0; r < 4; ++r)
            As[(wv * 16 + quad * 4 + r) * 72 + t * 16 + mn] = f2bf(acc[t][r] * dv[r]);
    __syncthreads();
#pragma unroll
    for (int it = 0; it < 2; ++it) {
        int i = tid + 256 * it;
        int row = i >> 3, c8 = (i & 7) << 3;
        int gr = row0 + row;
        if (gr < NN) *(uint4*)(y + (size_t)gr * 64 + c8) = *(uint4*)&As[row * 72 + c8];
    }
}

// ---------------- GEMM hidden: bf16 A direct global, bf16 WT direct global, LDS only for epilogue ----------------
__global__ __launch_bounds__(256) void gemmH_mfma(const unsigned short* __restrict__ xb,
                                                  const unsigned short* __restrict__ WT,
                                                  const float* __restrict__ dinv, unsigned short* __restrict__ y) {
    __shared__ unsigned short As[64 * 72];
    const int tid = threadIdx.x;
    const int wv = tid >> 6, lane = tid & 63;
    const int mn = lane & 15, quad = lane >> 4;
    const int row0 = blockIdx.x * 64;
    const unsigned arow = (unsigned)(row0 + wv * 16 + mn);

    f32x4 acc[4];
#pragma unroll
    for (int t = 0; t < 4; ++t) acc[t] = (f32x4){0.f, 0.f, 0.f, 0.f};

#pragma unroll
    for (int kk = 0; kk < 2; ++kk) {
        bf16x8 a = *(const bf16x8*)(xb + (arow << 6) + kk * 32 + quad * 8);
#pragma unroll
        for (int t = 0; t < 4; ++t) {
            bf16x8 bfr = *(const bf16x8*)(WT + ((t * 16 + mn) << 6) + kk * 32 + quad * 8);
            acc[t] = __builtin_amdgcn_mfma_f32_16x16x32_bf16(a, bfr, acc[t], 0, 0, 0);
        }
    }
    float dv[4];
#pragma unroll
    for (int r = 0; r < 4; ++r) {
        int gr = row0 + wv * 16 + quad * 4 + r;
        dv[r] = (gr < NN) ? dinv[gr] : 0.f;
    }
#pragma unroll
    for (int t = 0; t < 4; ++t)
#pragma unroll
        for (int r = 0; r < 4; ++r)
            As[(wv * 16 + quad * 4 + r) * 72 + t * 16 + mn] = f2bf(acc[t][r] * dv[r]);
    __syncthreads();
#pragma unroll
    for (int it = 0; it < 2; ++it) {
        int i = tid + 256 * it;
        int row = i >> 3, c8 = (i & 7) << 3;
        int gr = row0 + row;
        if (gr < NN) *(uint4*)(y + (size_t)gr * 64 + c8) = *(uint4*)&As[row * 72 + c8];
    }
}

// ---------------- Aggregate core: wave = 1 dst; 8 slots x 8 lanes; lane = uint4 (8 bf16) ----------------
__device__ __forceinline__ void agg_core8(const unsigned short* __restrict__ y, const int* __restrict__ col,
                                          int d, int s0, int s1, int g, int h0, float dv,
                                          const float* __restrict__ b, float* __restrict__ r) {
    float2 accA[4] = {{0.f, 0.f}, {0.f, 0.f}, {0.f, 0.f}, {0.f, 0.f}};
    float2 accB[4] = {{0.f, 0.f}, {0.f, 0.f}, {0.f, 0.f}, {0.f, 0.f}};
    if (g == 0) {
        uint4 v = *(const uint4*)(y + (((unsigned)d) << 6) + h0);
        acc_u4(accA, v);
    }
    int e = s0;
    for (; e + 32 <= s1; e += 32) {
        int a0 = col[e + g], a1 = col[e + 8 + g], a2 = col[e + 16 + g], a3 = col[e + 24 + g];
        uint4 v0 = *(const uint4*)(y + (((unsigned)a0) << 6) + h0);
        uint4 v1 = *(const uint4*)(y + (((unsigned)a1) << 6) + h0);
        uint4 v2 = *(const uint4*)(y + (((unsigned)a2) << 6) + h0);
        uint4 v3 = *(const uint4*)(y + (((unsigned)a3) << 6) + h0);
        acc_u4(accA, v0); acc_u4(accB, v1); acc_u4(accA, v2); acc_u4(accB, v3);
    }
    for (; e + 8 <= s1; e += 8) {
        int a0 = col[e + g];
        uint4 v0 = *(const uint4*)(y + (((unsigned)a0) << 6) + h0);
        acc_u4(accA, v0);
    }
    if (e + g < s1) {
        int a0 = col[e + g];
        uint4 v0 = *(const uint4*)(y + (((unsigned)a0) << 6) + h0);
        acc_u4(accB, v0);
    }
#pragma unroll
    for (int j = 0; j < 4; ++j) {
        float sx = accA[j].x + accB[j].x;
        float sy = accA[j].y + accB[j].y;
        sx += __shfl_xor(sx, 8); sx += __shfl_xor(sx, 16); sx += __shfl_xor(sx, 32);
        sy += __shfl_xor(sy, 8); sy += __shfl_xor(sy, 16); sy += __shfl_xor(sy, 32);
        r[2 * j] = dv * sx + b[h0 + 2 * j];
        r[2 * j + 1] = dv * sy + b[h0 + 2 * j + 1];
    }
}

// Aggregate -> bf16 output (feeds next GEMM's A; rounding there anyway)
__global__ __launch_bounds__(256) void aggregate_kernel(const unsigned short* __restrict__ y,
                                                        const int* __restrict__ row_beg, const int* __restrict__ row_end,
                                                        const int* __restrict__ col, const float* __restrict__ dinv,
                                                        const float* __restrict__ b, unsigned short* __restrict__ xout,
                                                        int relu) {
    const int tid = threadIdx.x;
    const int wv = tid >> 6, lane = tid & 63;
    const int g = lane >> 3, l = lane & 7;
    const int h0 = l << 3;
    const int d = blockIdx.x * 4 + wv;
    const int s0 = row_beg[d], s1 = row_end[d];
    float r[8];
    agg_core8(y, col, d, s0, s1, g, h0, dinv[d], b, r);
    if (relu) {
#pragma unroll
        for (int j = 0; j < 8; ++j) r[j] = fmaxf(r[j], 0.f);
    }
    if (g == 0) {
        uint4 o;
        o.x = (unsigned)f2bf(r[0]) | ((unsigned)f2bf(r[1]) << 16);
        o.y = (unsigned)f2bf(r[2]) | ((unsigned)f2bf(r[3]) << 16);
        o.z = (unsigned)f2bf(r[4]) | ((unsigned)f2bf(r[5]) << 16);
        o.w = (unsigned)f2bf(r[6]) | ((unsigned)f2bf(r[7]) << 16);
        *(uint4*)(xout + (((unsigned)d) << 6) + h0) = o;
    }
}

// Layer-2 aggregate fused with relu -> L2 normalize -> write h -> logits -> log_softmax -> pred
__global__ __launch_bounds__(256) void aggregate_final_kernel(const unsigned short* __restrict__ y,
                                                              const int* __restrict__ row_beg, const int* __restrict__ row_end,
                                                              const int* __restrict__ col, const float* __restrict__ dinv,
                                                              const float* __restrict__ b,
                                                              const float* __restrict__ W3, const float* __restrict__ b3,
                                                              float* __restrict__ out) {
    const int tid = threadIdx.x;
    const int wv = tid >> 6, lane = tid & 63;
    const int g = lane >> 3, l = lane & 7;
    const int h0 = l << 3;
    const int d = blockIdx.x * 4 + wv;
    const int s0 = row_beg[d], s1 = row_end[d];
    float r[8];
    agg_core8(y, col, d, s0, s1, g, h0, dinv[d], b, r);
#pragma unroll
    for (int j = 0; j < 8; ++j) r[j] = fmaxf(r[j], 0.f);

    float sq = 0.f;
#pragma unroll
    for (int j = 0; j < 8; ++j) sq += r[j] * r[j];
    sq += __shfl_xor(sq, 1);
    sq += __shfl_xor(sq, 2);
    sq += __shfl_xor(sq, 4);
    float inv = 1.0f / fmaxf(sqrtf(sq), 1e-12f);

    __shared__ float hl[4][64];
    if (g == 0) {
        float4 hA = make_float4(r[0] * inv, r[1] * inv, r[2] * inv, r[3] * inv);
        float4 hB = make_float4(r[4] * inv, r[5] * inv, r[6] * inv, r[7] * inv);
        float* op = out + 1 + (size_t)NN * C_DIM + (size_t)d * 64 + h0;
        *(float4*)op = hA;
        *(float4*)(op + 4) = hB;
        *(float4*)&hl[wv][h0] = hA;
        *(float4*)&hl[wv][h0 + 4] = hB;
    }
    __syncthreads();

    int c = lane & 15, chunk = lane >> 4;
    float part = 0.f;
#pragma unroll
    for (int q = 0; q < 16; ++q) {
        int hh = chunk * 16 + q;
        part += hl[wv][hh] * W3[hh * 16 + c];
    }
    part += __shfl_xor(part, 16);
    part += __shfl_xor(part, 32);
    float logit = part + b3[c];

    float m = logit;
#pragma unroll
    for (int off = 8; off > 0; off >>= 1) m = fmaxf(m, __shfl_xor(m, off));
    float ex = __expf(logit - m);
    float se = ex;
#pragma unroll
    for (int off = 8; off > 0; off >>= 1) se += __shfl_xor(se, off);
    float pred = logit - m - __logf(se);
    if (lane < 16) out[1 + (size_t)d * 16 + lane] = pred;
}

__global__ __launch_bounds__(256) void loss_kernel(const float* __restrict__ out, const int* __restrict__ labels,
                                                   const int* __restrict__ train_idx, float* __restrict__ loss_ws) {
    int i = blockIdx.x * 256 + threadIdx.x;
    float v = 0.f;
    if (i < NT) {
        int idx = train_idx[i];
        int lab = labels[idx];
        v = -out[1 + (size_t)idx * 16 + lab];
    }
#pragma unroll
    for (int off = 32; off > 0; off >>= 1) v += __shfl_xor(v, off);
    __shared__ float ws4[4];
    int wv = threadIdx.x >> 6, lane = threadIdx.x & 63;
    if (lane == 0) ws4[wv] = v;
    __syncthreads();
    if (threadIdx.x == 0) atomicAdd(loss_ws, ws4[0] + ws4[1] + ws4[2] + ws4[3]);
}

__global__ void finalize_kernel(const float* __restrict__ loss_ws, float* __restrict__ out) {
    if (threadIdx.x == 0) out[0] = loss_ws[0] * (1.0f / NT);
}

// ---------------- launch ----------------

extern "C" void kernel_launch(void* const* d_in, const int* in_sizes, int n_in,
                              void* d_out, int out_size, void* d_ws, size_t ws_size,
                              hipStream_t stream) {
    const float* feats = (const float*)d_in[0];
    const float* W1 = (const float*)d_in[1];
    const float* b1 = (const float*)d_in[2];
    const float* W2 = (const float*)d_in[3];
    const float* b2 = (const float*)d_in[4];
    const float* W3 = (const float*)d_in[5];
    const float* b3 = (const float*)d_in[6];
    const int* edge_list = (const int*)d_in[7];
    const int* labels = (const int*)d_in[8];
    const int* train_idx = (const int*)d_in[9];
    float* out = (float*)d_out;

    char* w = (char*)d_ws;
    auto alloc = [&](size_t bytes) {
        char* p = w;
        w += (bytes + 255) & ~(size_t)255;
        return p;
    };
    int* row_beg = (int*)alloc((size_t)NN * 4);
    int* row_end = (int*)alloc((size_t)NN * 4);
    int* col = (int*)alloc((size_t)NBUK * PAD * 4);
    unsigned int* temp = (unsigned int*)alloc((size_t)NBUK * PAD * 4);
    float* dinv = (float*)alloc((size_t)NN * 4);
    unsigned short* yb = (unsigned short*)alloc((size_t)(NN + 64) * 64 * 2);
    unsigned short* xb = (unsigned short*)alloc((size_t)(NN + 64) * 64 * 2);
    unsigned short* WT1 = (unsigned short*)alloc((size_t)64 * 256 * 2);
    unsigned short* WT2 = (unsigned short*)alloc((size_t)2 * 64 * 64 * 2);
    float* loss_ws = (float*)alloc(4);
    int* cursor = (int*)alloc((size_t)NBUK * 4);

    const int* srcp = edge_list;
    const int* dstp = edge_list + EE;

    zero_kernel<<<2, 256, 0, stream>>>(cursor, loss_ws);
    prep_weights<<<96, 256, 0, stream>>>(W1, W2, WT1, WT2);
    multisplit_kernel<<<NCHUNK, 256, 0, stream>>>(srcp, dstp, cursor, temp);
    bucket_finalize_kernel<<<NBUK, 256, 0, stream>>>(temp, cursor, row_beg, row_end, dinv, col);

    const int GB = (NN + 63) / 64;  // 782
    // layer 0
    gemm0_mfma<<<GB, 256, 0, stream>>>(feats, WT1, dinv, yb);
    aggregate_kernel<<<NN / 4, 256, 0, stream>>>(yb, row_beg, row_end, col, dinv, b1, xb, 0);
    // layer 1
    gemmH_mfma<<<GB, 256, 0, stream>>>(xb, WT2, dinv, yb);
    aggregate_kernel<<<NN / 4, 256, 0, stream>>>(yb, row_beg, row_end, col, dinv, b2, xb, 1);
    // layer 2 + fused tail
    gemmH_mfma<<<GB, 256, 0, stream>>>(xb, WT2 + 4096, dinv, yb);
    aggregate_final_kernel<<<NN / 4, 256, 0, stream>>>(yb, row_beg, row_end, col, dinv, b2 + H_DIM, W3, b3, out);

    loss_kernel<<<(NT + 255) / 256, 256, 0, stream>>>(out, labels, train_idx, loss_ws);
    finalize_kernel<<<1, 64, 0, stream>>>(loss_ws, out);
}

// Round 10
// 278.653 us; speedup vs baseline: 2.5866x; 1.0468x over previous
//
#include <hip/hip_runtime.h>
#include <math.h>

#define NN 50000
#define EE 1600000
#define IN_DIM 256
#define H_DIM 64
#define C_DIM 16
#define NT 5000
#define NBUK 391  // ceil(NN/128)
#define CHUNK 8192
#define NCHUNK 196  // ceil(EE/CHUNK)
#define PAD 6144   // per-bucket capacity (expected load ~4092+pad<=~4900)
#define CAP 6144

typedef short bf16x8 __attribute__((ext_vector_type(8)));
typedef float f32x4 __attribute__((ext_vector_type(4)));

__device__ __forceinline__ unsigned short f2bf(float f) {
    unsigned int u = __float_as_uint(f);
    u = (u + 0x7FFFu + ((u >> 16) & 1u)) >> 16;  // RNE
    return (unsigned short)u;
}
__device__ __forceinline__ void acc_dw(float2& a, unsigned u) {
    float2 t;
    t.x = __uint_as_float(u << 16);
    t.y = __uint_as_float(u & 0xFFFF0000u);
    a.x += t.x;
    a.y += t.y;
}
__device__ __forceinline__ void acc_u4(float2* acc, uint4 v) {
    acc_dw(acc[0], v.x); acc_dw(acc[1], v.y); acc_dw(acc[2], v.z); acc_dw(acc[3], v.w);
}

// ---------------- init: cursors, loss, bf16-transposed weights ----------------
__global__ __launch_bounds__(256) void init_kernel(const float* __restrict__ W1, const float* __restrict__ W2,
                                                   unsigned short* __restrict__ WT1, unsigned short* __restrict__ WT2,
                                                   int* __restrict__ cursor, float* __restrict__ loss_ws) {
    int i = blockIdx.x * 256 + threadIdx.x;
    if (i < NBUK) cursor[i] = i * PAD;
    if (i == 0) loss_ws[0] = 0.f;
    if (i < 64 * 256) {
        int n = i >> 8, k = i & 255;
        WT1[i] = f2bf(W1[k * 64 + n]);
    }
    int j = i - 64 * 256;
    if (j >= 0 && j < 2 * 64 * 64) {
        int l = j >> 12, r = j & 4095;
        int n = r >> 6, k = r & 63;
        WT2[j] = f2bf(W2[l * 4096 + k * 64 + n]);
    }
}

// ---------------- multisplit into padded per-bucket regions ----------------
// stag packs (b<<23)|(dlow<<16)|src -- 9+7+16 = 32 bits (src < 65536).
__global__ __launch_bounds__(256) void multisplit_kernel(const int* __restrict__ src, const int* __restrict__ dst,
                                                         int* __restrict__ cursor, unsigned int* __restrict__ temp) {
    __shared__ int hist[NBUK];
    __shared__ int excl[NBUK + 1];
    __shared__ int offs[NBUK];
    __shared__ int delta[NBUK];
    __shared__ unsigned int stag[CHUNK];

    const int tid = threadIdx.x;
    const int base_e = blockIdx.x * CHUNK;

    for (int i = tid; i < NBUK; i += 256) hist[i] = 0;
    __syncthreads();

    for (int i = tid; i < CHUNK; i += 256) {
        int e = base_e + i;
        if (e < EE) atomicAdd(&hist[dst[e] >> 7], 1);
    }
    __syncthreads();

    if (tid < 64) {
        int lane = tid;
        int lc[7];
        int s = 0;
#pragma unroll
        for (int k = 0; k < 7; ++k) {
            int idx = lane * 7 + k;
            int c = (idx < NBUK) ? hist[idx] : 0;
            lc[k] = c;
            s += c;
        }
        int v = s;
#pragma unroll
        for (int off = 1; off < 64; off <<= 1) {
            int u = __shfl_up(v, off);
            if (lane >= off) v += u;
        }
        int ex = v - s;
#pragma unroll
        for (int k = 0; k < 7; ++k) {
            int idx = lane * 7 + k;
            if (idx < NBUK) excl[idx] = ex;
            ex += lc[k];
        }
        if (lane == 63) excl[NBUK] = v;
    }
    __syncthreads();

    for (int b = tid; b < NBUK; b += 256) {
        int count = excl[b + 1] - excl[b];
        int gbase = atomicAdd(&cursor[b], count);
        delta[b] = gbase - excl[b];
        offs[b] = excl[b];
    }
    __syncthreads();

    for (int i = tid; i < CHUNK; i += 256) {
        int e = base_e + i;
        if (e < EE) {
            int d = dst[e];
            int s = src[e];
            int b = d >> 7;
            int rank = atomicAdd(&offs[b], 1);
            stag[rank] = ((unsigned)b << 23) | ((unsigned)(d & 127) << 16) | (unsigned)s;
        }
    }
    __syncthreads();

    int nval = excl[NBUK];
    for (int i = tid; i < nval; i += 256) {
        unsigned int v = stag[i];
        temp[delta[v >> 23] + i] = v & 0x7FFFFFu;
    }
}

// ---------------- per-bucket finalize: counts (padded to x8) -> row_beg/row_end + dinv, place col ----------------
__global__ __launch_bounds__(256) void bucket_finalize_kernel(const unsigned int* __restrict__ temp,
                                                              const int* __restrict__ cursor,
                                                              int* __restrict__ row_beg, int* __restrict__ row_end,
                                                              float* __restrict__ dinv, int* __restrict__ col) {
    __shared__ int cnt_l[128];
    __shared__ int exc[129];
    __shared__ int cur[128];
    __shared__ unsigned int stag[CAP];
    __shared__ int stag2[CAP];
    const int b = blockIdx.x;
    const int tid = threadIdx.x;
    const int d0 = b << 7;
    const int nd = (d0 + 128 < NN) ? 128 : (NN - d0);
    const int base = b * PAD;
    int M = cursor[b] - base;
    if (M > CAP) M = CAP;  // statistically unreachable

    for (int j = tid; j < 128; j += 256) cnt_l[j] = 0;
    __syncthreads();

    for (int i = tid; i < M; i += 256) {
        unsigned int v = temp[base + i];
        stag[i] = v;
        atomicAdd(&cnt_l[(v >> 16) & 127], 1);
    }
    __syncthreads();

    // exclusive scan of PADDED counts (each row rounded up to multiple of 8)
    if (tid < 64) {
        int c0 = (cnt_l[2 * tid] + 7) & ~7;
        int c1 = (cnt_l[2 * tid + 1] + 7) & ~7;
        int s = c0 + c1;
        int v = s;
#pragma unroll
        for (int off = 1; off < 64; off <<= 1) {
            int u = __shfl_up(v, off);
            if (tid >= off) v += u;
        }
        int ex = v - s;
        exc[2 * tid] = ex;
        exc[2 * tid + 1] = ex + c0;
        if (tid == 63) exc[128] = v;  // == M_pad
    }
    __syncthreads();
    const int Mp = exc[128];

    if (tid < nd) {
        row_beg[d0 + tid] = base + exc[tid];
        row_end[d0 + tid] = base + exc[tid + 1];
        dinv[d0 + tid] = rsqrtf((float)(cnt_l[tid] + 1));  // +1 self-loop (real degree)
    }

    if (tid < 128) cur[tid] = exc[tid];
    // init padded slots to the zero row NN
    for (int i = tid; i < Mp; i += 256) stag2[i] = NN;
    __syncthreads();

    for (int i = tid; i < M; i += 256) {
        unsigned int v = stag[i];
        int r = atomicAdd(&cur[(v >> 16) & 127], 1);
        stag2[r] = (int)(v & 0xFFFFu);
    }
    __syncthreads();
    for (int i = tid; i < Mp; i += 256) col[base + i] = stag2[i];
}

// ---------------- GEMM layer 0: fp32 feats (LDS-staged, cvt) x WT1 (direct global B frags) ----------------
__global__ __launch_bounds__(256) void gemm0_mfma(const float* __restrict__ x, const unsigned short* __restrict__ WT,
                                                  const float* __restrict__ dinv, unsigned short* __restrict__ y) {
    __shared__ unsigned short As[64 * 72];
    const int tid = threadIdx.x;
    const int wv = tid >> 6, lane = tid & 63;
    const int mn = lane & 15, quad = lane >> 4;
    const int row0 = blockIdx.x * 64;

    f32x4 acc[4];
#pragma unroll
    for (int t = 0; t < 4; ++t) acc[t] = (f32x4){0.f, 0.f, 0.f, 0.f};

    for (int k0 = 0; k0 < 256; k0 += 64) {
        __syncthreads();
#pragma unroll
        for (int it = 0; it < 4; ++it) {
            int i = tid + 256 * it;
            int row = i >> 4, c4 = (i & 15) << 2;
            int gr = row0 + row;
            float4 v = make_float4(0.f, 0.f, 0.f, 0.f);
            if (gr < NN) v = *(const float4*)(x + (size_t)gr * 256 + k0 + c4);
            ushort4 o;
            o.x = f2bf(v.x); o.y = f2bf(v.y); o.z = f2bf(v.z); o.w = f2bf(v.w);
            *(ushort4*)&As[row * 72 + c4] = o;
        }
        __syncthreads();
#pragma unroll
        for (int kk = 0; kk < 2; ++kk) {
            bf16x8 a = *(const bf16x8*)&As[(wv * 16 + mn) * 72 + kk * 32 + quad * 8];
#pragma unroll
            for (int t = 0; t < 4; ++t) {
                bf16x8 bfr = *(const bf16x8*)(WT + (t * 16 + mn) * 256 + k0 + kk * 32 + quad * 8);
                acc[t] = __builtin_amdgcn_mfma_f32_16x16x32_bf16(a, bfr, acc[t], 0, 0, 0);
            }
        }
    }
    __syncthreads();
    float dv[4];
#pragma unroll
    for (int r = 0; r < 4; ++r) {
        int gr = row0 + wv * 16 + quad * 4 + r;
        dv[r] = (gr < NN) ? dinv[gr] : 0.f;
    }
#pragma unroll
    for (int t = 0; t < 4; ++t)
#pragma unroll
        for (int r = 0; r < 4; ++r)
            As[(wv * 16 + quad * 4 + r) * 72 + t * 16 + mn] = f2bf(acc[t][r] * dv[r]);
    __syncthreads();
#pragma unroll
    for (int it = 0; it < 2; ++it) {
        int i = tid + 256 * it;
        int row = i >> 3, c8 = (i & 7) << 3;
        int gr = row0 + row;
        if (gr < NN) *(uint4*)(y + (size_t)gr * 64 + c8) = *(uint4*)&As[row * 72 + c8];
    }
    // zero row NN (gather target for padded CSR slots)
    if (blockIdx.x == 0 && tid < 8) {
        uint4 z = {0u, 0u, 0u, 0u};
        *(uint4*)(y + (size_t)NN * 64 + tid * 8) = z;
    }
}

// ---------------- GEMM hidden: bf16 A direct global, bf16 WT direct global, LDS only for epilogue ----------------
__global__ __launch_bounds__(256) void gemmH_mfma(const unsigned short* __restrict__ xb,
                                                  const unsigned short* __restrict__ WT,
                                                  const float* __restrict__ dinv, unsigned short* __restrict__ y) {
    __shared__ unsigned short As[64 * 72];
    const int tid = threadIdx.x;
    const int wv = tid >> 6, lane = tid & 63;
    const int mn = lane & 15, quad = lane >> 4;
    const int row0 = blockIdx.x * 64;
    const unsigned arow = (unsigned)(row0 + wv * 16 + mn);

    f32x4 acc[4];
#pragma unroll
    for (int t = 0; t < 4; ++t) acc[t] = (f32x4){0.f, 0.f, 0.f, 0.f};

#pragma unroll
    for (int kk = 0; kk < 2; ++kk) {
        bf16x8 a = *(const bf16x8*)(xb + (arow << 6) + kk * 32 + quad * 8);
#pragma unroll
        for (int t = 0; t < 4; ++t) {
            bf16x8 bfr = *(const bf16x8*)(WT + ((t * 16 + mn) << 6) + kk * 32 + quad * 8);
            acc[t] = __builtin_amdgcn_mfma_f32_16x16x32_bf16(a, bfr, acc[t], 0, 0, 0);
        }
    }
    float dv[4];
#pragma unroll
    for (int r = 0; r < 4; ++r) {
        int gr = row0 + wv * 16 + quad * 4 + r;
        dv[r] = (gr < NN) ? dinv[gr] : 0.f;
    }
#pragma unroll
    for (int t = 0; t < 4; ++t)
#pragma unroll
        for (int r = 0; r < 4; ++r)
            As[(wv * 16 + quad * 4 + r) * 72 + t * 16 + mn] = f2bf(acc[t][r] * dv[r]);
    __syncthreads();
#pragma unroll
    for (int it = 0; it < 2; ++it) {
        int i = tid + 256 * it;
        int row = i >> 3, c8 = (i & 7) << 3;
        int gr = row0 + row;
        if (gr < NN) *(uint4*)(y + (size_t)gr * 64 + c8) = *(uint4*)&As[row * 72 + c8];
    }
    if (blockIdx.x == 0 && tid < 8) {
        uint4 z = {0u, 0u, 0u, 0u};
        *(uint4*)(y + (size_t)NN * 64 + tid * 8) = z;
    }
}

// ---------------- Aggregate core: wave = 1 dst; 8 slots x 8 lanes; lane = uint4 (8 bf16) ----------------
// Rows padded to x8 (pad slots point at zero row NN): no scalar tail.
// col for next 32-block prefetched before unpacking current y (hides col->y chain).
__device__ __forceinline__ void agg_core8(const unsigned short* __restrict__ y, const int* __restrict__ col,
                                          int d, int s0, int s1, int g, int h0, float dv,
                                          const float* __restrict__ b, float* __restrict__ r) {
    float2 accA[4] = {{0.f, 0.f}, {0.f, 0.f}, {0.f, 0.f}, {0.f, 0.f}};
    float2 accB[4] = {{0.f, 0.f}, {0.f, 0.f}, {0.f, 0.f}, {0.f, 0.f}};
    if (g == 0) {
        uint4 v = *(const uint4*)(y + (((unsigned)d) << 6) + h0);
        acc_u4(accA, v);
    }
    int e = s0;
    int rem = s1 - s0;  // multiple of 8
    int a0, a1, a2, a3;
    if (rem >= 32) {
        a0 = col[e + g]; a1 = col[e + 8 + g]; a2 = col[e + 16 + g]; a3 = col[e + 24 + g];
    }
    while (rem >= 32) {
        uint4 v0 = *(const uint4*)(y + (((unsigned)a0) << 6) + h0);
        uint4 v1 = *(const uint4*)(y + (((unsigned)a1) << 6) + h0);
        uint4 v2 = *(const uint4*)(y + (((unsigned)a2) << 6) + h0);
        uint4 v3 = *(const uint4*)(y + (((unsigned)a3) << 6) + h0);
        e += 32; rem -= 32;
        int n0, n1, n2, n3;
        if (rem >= 32) {
            n0 = col[e + g]; n1 = col[e + 8 + g]; n2 = col[e + 16 + g]; n3 = col[e + 24 + g];
        }
        acc_u4(accA, v0); acc_u4(accB, v1); acc_u4(accA, v2); acc_u4(accB, v3);
        if (rem >= 32) { a0 = n0; a1 = n1; a2 = n2; a3 = n3; }
    }
    // remainder: 0, 8, 16, or 24 (wave-uniform)
    if (rem) {
        int c0 = col[e + g];
        int c1 = (rem > 8) ? col[e + 8 + g] : 0;
        int c2 = (rem > 16) ? col[e + 16 + g] : 0;
        uint4 v0 = *(const uint4*)(y + (((unsigned)c0) << 6) + h0);
        acc_u4(accA, v0);
        if (rem > 8) {
            uint4 v1 = *(const uint4*)(y + (((unsigned)c1) << 6) + h0);
            acc_u4(accB, v1);
        }
        if (rem > 16) {
            uint4 v2 = *(const uint4*)(y + (((unsigned)c2) << 6) + h0);
            acc_u4(accA, v2);
        }
    }
#pragma unroll
    for (int j = 0; j < 4; ++j) {
        float sx = accA[j].x + accB[j].x;
        float sy = accA[j].y + accB[j].y;
        sx += __shfl_xor(sx, 8); sx += __shfl_xor(sx, 16); sx += __shfl_xor(sx, 32);
        sy += __shfl_xor(sy, 8); sy += __shfl_xor(sy, 16); sy += __shfl_xor(sy, 32);
        r[2 * j] = dv * sx + b[h0 + 2 * j];
        r[2 * j + 1] = dv * sy + b[h0 + 2 * j + 1];
    }
}

// Aggregate -> bf16 output (feeds next GEMM's A; rounding there anyway)
__global__ __launch_bounds__(256) void aggregate_kernel(const unsigned short* __restrict__ y,
                                                        const int* __restrict__ row_beg, const int* __restrict__ row_end,
                                                        const int* __restrict__ col, const float* __restrict__ dinv,
                                                        const float* __restrict__ b, unsigned short* __restrict__ xout,
                                                        int relu) {
    const int tid = threadIdx.x;
    const int wv = tid >> 6, lane = tid & 63;
    const int g = lane >> 3, l = lane & 7;
    const int h0 = l << 3;
    const int d = blockIdx.x * 4 + wv;
    const int s0 = row_beg[d], s1 = row_end[d];
    float r[8];
    agg_core8(y, col, d, s0, s1, g, h0, dinv[d], b, r);
    if (relu) {
#pragma unroll
        for (int j = 0; j < 8; ++j) r[j] = fmaxf(r[j], 0.f);
    }
    if (g == 0) {
        uint4 o;
        o.x = (unsigned)f2bf(r[0]) | ((unsigned)f2bf(r[1]) << 16);
        o.y = (unsigned)f2bf(r[2]) | ((unsigned)f2bf(r[3]) << 16);
        o.z = (unsigned)f2bf(r[4]) | ((unsigned)f2bf(r[5]) << 16);
        o.w = (unsigned)f2bf(r[6]) | ((unsigned)f2bf(r[7]) << 16);
        *(uint4*)(xout + (((unsigned)d) << 6) + h0) = o;
    }
}

// Layer-2 aggregate fused with relu -> L2 normalize -> write h -> logits -> log_softmax -> pred
__global__ __launch_bounds__(256) void aggregate_final_kernel(const unsigned short* __restrict__ y,
                                                              const int* __restrict__ row_beg, const int* __restrict__ row_end,
                                                              const int* __restrict__ col, const float* __restrict__ dinv,
                                                              const float* __restrict__ b,
                                                              const float* __restrict__ W3, const float* __restrict__ b3,
                                                              float* __restrict__ out) {
    const int tid = threadIdx.x;
    const int wv = tid >> 6, lane = tid & 63;
    const int g = lane >> 3, l = lane & 7;
    const int h0 = l << 3;
    const int d = blockIdx.x * 4 + wv;
    const int s0 = row_beg[d], s1 = row_end[d];
    float r[8];
    agg_core8(y, col, d, s0, s1, g, h0, dinv[d], b, r);
#pragma unroll
    for (int j = 0; j < 8; ++j) r[j] = fmaxf(r[j], 0.f);

    float sq = 0.f;
#pragma unroll
    for (int j = 0; j < 8; ++j) sq += r[j] * r[j];
    sq += __shfl_xor(sq, 1);
    sq += __shfl_xor(sq, 2);
    sq += __shfl_xor(sq, 4);
    float inv = 1.0f / fmaxf(sqrtf(sq), 1e-12f);

    __shared__ float hl[4][68];
    if (g == 0) {
        float4 hA = make_float4(r[0] * inv, r[1] * inv, r[2] * inv, r[3] * inv);
        float4 hB = make_float4(r[4] * inv, r[5] * inv, r[6] * inv, r[7] * inv);
        float* op = out + 1 + (size_t)NN * C_DIM + (size_t)d * 64 + h0;
        *(float4*)op = hA;
        *(float4*)(op + 4) = hB;
        *(float4*)&hl[wv][h0] = hA;
        *(float4*)&hl[wv][h0 + 4] = hB;
    }
    __syncthreads();

    int c = lane & 15, chunk = lane >> 4;
    float part = 0.f;
#pragma unroll
    for (int q = 0; q < 16; ++q) {
        int hh = chunk * 16 + q;
        part += hl[wv][hh] * W3[hh * 16 + c];
    }
    part += __shfl_xor(part, 16);
    part += __shfl_xor(part, 32);
    float logit = part + b3[c];

    float m = logit;
#pragma unroll
    for (int off = 8; off > 0; off >>= 1) m = fmaxf(m, __shfl_xor(m, off));
    float ex = __expf(logit - m);
    float se = ex;
#pragma unroll
    for (int off = 8; off > 0; off >>= 1) se += __shfl_xor(se, off);
    float pred = logit - m - __logf(se);
    if (lane < 16) out[1 + (size_t)d * 16 + lane] = pred;
}

__global__ __launch_bounds__(256) void loss_kernel(const float* __restrict__ out, const int* __restrict__ labels,
                                                   const int* __restrict__ train_idx, float* __restrict__ loss_ws) {
    int i = blockIdx.x * 256 + threadIdx.x;
    float v = 0.f;
    if (i < NT) {
        int idx = train_idx[i];
        int lab = labels[idx];
        v = -out[1 + (size_t)idx * 16 + lab];
    }
#pragma unroll
    for (int off = 32; off > 0; off >>= 1) v += __shfl_xor(v, off);
    __shared__ float ws4[4];
    int wv = threadIdx.x >> 6, lane = threadIdx.x & 63;
    if (lane == 0) ws4[wv] = v;
    __syncthreads();
    if (threadIdx.x == 0) atomicAdd(loss_ws, ws4[0] + ws4[1] + ws4[2] + ws4[3]);
}

__global__ void finalize_kernel(const float* __restrict__ loss_ws, float* __restrict__ out) {
    if (threadIdx.x == 0) out[0] = loss_ws[0] * (1.0f / NT);
}

// ---------------- launch ----------------

extern "C" void kernel_launch(void* const* d_in, const int* in_sizes, int n_in,
                              void* d_out, int out_size, void* d_ws, size_t ws_size,
                              hipStream_t stream) {
    const float* feats = (const float*)d_in[0];
    const float* W1 = (const float*)d_in[1];
    const float* b1 = (const float*)d_in[2];
    const float* W2 = (const float*)d_in[3];
    const float* b2 = (const float*)d_in[4];
    const float* W3 = (const float*)d_in[5];
    const float* b3 = (const float*)d_in[6];
    const int* edge_list = (const int*)d_in[7];
    const int* labels = (const int*)d_in[8];
    const int* train_idx = (const int*)d_in[9];
    float* out = (float*)d_out;

    char* w = (char*)d_ws;
    auto alloc = [&](size_t bytes) {
        char* p = w;
        w += (bytes + 255) & ~(size_t)255;
        return p;
    };
    int* row_beg = (int*)alloc((size_t)NN * 4);
    int* row_end = (int*)alloc((size_t)NN * 4);
    int* col = (int*)alloc((size_t)NBUK * PAD * 4);
    unsigned int* temp = (unsigned int*)alloc((size_t)NBUK * PAD * 4);
    float* dinv = (float*)alloc((size_t)NN * 4);
    unsigned short* yb = (unsigned short*)alloc((size_t)(NN + 64) * 64 * 2);
    unsigned short* xb = (unsigned short*)alloc((size_t)(NN + 64) * 64 * 2);
    unsigned short* WT1 = (unsigned short*)alloc((size_t)64 * 256 * 2);
    unsigned short* WT2 = (unsigned short*)alloc((size_t)2 * 64 * 64 * 2);
    float* loss_ws = (float*)alloc(4);
    int* cursor = (int*)alloc((size_t)NBUK * 4);

    const int* srcp = edge_list;
    const int* dstp = edge_list + EE;

    init_kernel<<<96, 256, 0, stream>>>(W1, W2, WT1, WT2, cursor, loss_ws);
    multisplit_kernel<<<NCHUNK, 256, 0, stream>>>(srcp, dstp, cursor, temp);
    bucket_finalize_kernel<<<NBUK, 256, 0, stream>>>(temp, cursor, row_beg, row_end, dinv, col);

    const int GB = (NN + 63) / 64;  // 782
    // layer 0
    gemm0_mfma<<<GB, 256, 0, stream>>>(feats, WT1, dinv, yb);
    aggregate_kernel<<<NN / 4, 256, 0, stream>>>(yb, row_beg, row_end, col, dinv, b1, xb, 0);
    // layer 1
    gemmH_mfma<<<GB, 256, 0, stream>>>(xb, WT2, dinv, yb);
    aggregate_kernel<<<NN / 4, 256, 0, stream>>>(yb, row_beg, row_end, col, dinv, b2, xb, 1);
    // layer 2 + fused tail
    gemmH_mfma<<<GB, 256, 0, stream>>>(xb, WT2 + 4096, dinv, yb);
    aggregate_final_kernel<<<NN / 4, 256, 0, stream>>>(yb, row_beg, row_end, col, dinv, b2 + H_DIM, W3, b3, out);

    loss_kernel<<<(NT + 255) / 256, 256, 0, stream>>>(out, labels, train_idx, loss_ws);
    finalize_kernel<<<1, 64, 0, stream>>>(loss_ws, out);
}